// Round 3
// baseline (1756.406 us; speedup 1.0000x reference)
//
#include <hip/hip_runtime.h>

#define HDIM 64
#define EPS_F 1e-16f

// ---------------------------------------------------------------------------
// vd[k] = sum_j Wd[k][j] * a_d[j]   (din <= 128, trivial)
// ---------------------------------------------------------------------------
__global__ void compute_vd_kernel(const float* __restrict__ Wd,
                                  const float* __restrict__ ad,
                                  float* __restrict__ vd, int din) {
    int k = blockIdx.x * blockDim.x + threadIdx.x;
    if (k >= din) return;
    float s = 0.f;
#pragma unroll
    for (int j = 0; j < HDIM; ++j) s = fmaf(Wd[k * HDIM + j], ad[j], s);
    vd[k] = s;
}

// ---------------------------------------------------------------------------
// Fused: hs = x @ Ws ;  als = hs . a_s ;  ald = x . vd
// Block = 256 threads, 32 nodes/block, 8 threads/node, 8 outputs/thread.
// ---------------------------------------------------------------------------
template <int DIN>
__global__ __launch_bounds__(256) void gemm_fused_kernel(
    const float* __restrict__ xin, const float* __restrict__ Ws,
    const float* __restrict__ as_, const float* __restrict__ vd,
    float* __restrict__ hs, float* __restrict__ als, float* __restrict__ ald,
    int N) {
    __shared__ float wsh[DIN * HDIM];
    __shared__ float xs[32 * (DIN + 4)];   // +4 pad: keeps 16B align, kills bank conflicts
    __shared__ float ash[HDIM];
    __shared__ float vdsh[DIN];

    const int tid = threadIdx.x;
    const int n0 = blockIdx.x * 32;

    for (int i = tid * 4; i < DIN * HDIM; i += 256 * 4)
        *(float4*)&wsh[i] = *(const float4*)&Ws[i];
    if (tid < HDIM) ash[tid] = as_[tid];
    if (tid < DIN) vdsh[tid] = vd[tid];
    for (int i = tid; i < 32 * DIN / 4; i += 256) {
        int idx = i * 4;
        int n = idx / DIN, k = idx - n * DIN;
        float4 v = make_float4(0.f, 0.f, 0.f, 0.f);
        if (n0 + n < N) v = *(const float4*)&xin[(size_t)(n0 + n) * DIN + k];
        *(float4*)&xs[n * (DIN + 4) + k] = v;
    }
    __syncthreads();

    const int nl = tid >> 3, jg = tid & 7, j0 = jg * 8;
    const int n = n0 + nl;
    float acc[8] = {0.f, 0.f, 0.f, 0.f, 0.f, 0.f, 0.f, 0.f};
    float aldp = 0.f;
    const float* xrow = &xs[nl * (DIN + 4)];
#pragma unroll 4
    for (int k = 0; k < DIN; ++k) {
        float xv = xrow[k];
        aldp = fmaf(xv, vdsh[k], aldp);
        float4 w0 = *(const float4*)&wsh[k * HDIM + j0];
        float4 w1 = *(const float4*)&wsh[k * HDIM + j0 + 4];
        acc[0] = fmaf(xv, w0.x, acc[0]);
        acc[1] = fmaf(xv, w0.y, acc[1]);
        acc[2] = fmaf(xv, w0.z, acc[2]);
        acc[3] = fmaf(xv, w0.w, acc[3]);
        acc[4] = fmaf(xv, w1.x, acc[4]);
        acc[5] = fmaf(xv, w1.y, acc[5]);
        acc[6] = fmaf(xv, w1.z, acc[6]);
        acc[7] = fmaf(xv, w1.w, acc[7]);
    }
    float alsp = 0.f;
#pragma unroll
    for (int jj = 0; jj < 8; ++jj) alsp = fmaf(acc[jj], ash[j0 + jj], alsp);
    alsp += __shfl_down(alsp, 4, 8);
    alsp += __shfl_down(alsp, 2, 8);
    alsp += __shfl_down(alsp, 1, 8);

    if (n < N) {
        *(float4*)&hs[(size_t)n * HDIM + j0] =
            make_float4(acc[0], acc[1], acc[2], acc[3]);
        *(float4*)&hs[(size_t)n * HDIM + j0 + 4] =
            make_float4(acc[4], acc[5], acc[6], acc[7]);
        if (jg == 0) {
            als[n] = alsp;
            ald[n] = aldp;
        }
    }
}

// ---------------------------------------------------------------------------
// Per-layer init: out = bias broadcast; segmax = 0 (valid: logits >= 0); denom = 0
// ---------------------------------------------------------------------------
__global__ void init_layer_kernel(float* __restrict__ out, const float* __restrict__ b,
                                  float* __restrict__ segmax, float* __restrict__ denom,
                                  int N) {
    int i = blockIdx.x * blockDim.x + threadIdx.x;
    int total = N * HDIM;
    if (i < total) out[i] = b[i & (HDIM - 1)];
    if (i < N) {
        segmax[i] = 0.f;
        denom[i] = 0.f;
    }
}

// ---------------------------------------------------------------------------
// Pass 1 over edges: logit = relu(als[src] + ald[dst]); seg-max via int atomicMax
// (float bits order == int order for non-negative floats)
// ---------------------------------------------------------------------------
__global__ void edge_logit_kernel(const int* __restrict__ src, const int* __restrict__ dst,
                                  const float* __restrict__ als, const float* __restrict__ ald,
                                  float* __restrict__ logit, float* __restrict__ segmax,
                                  int E) {
    int e = blockIdx.x * blockDim.x + threadIdx.x;
    if (e >= E) return;
    int s = src[e], d = dst[e];
    float l = als[s] + ald[d];
    l = l > 0.f ? l : 0.f;
    logit[e] = l;
    atomicMax((int*)segmax + d, __float_as_int(l));
}

// ---------------------------------------------------------------------------
// Pass 2: ex = exp(logit - segmax[dst]); denom[dst] += ex; store ex in place
// ---------------------------------------------------------------------------
__global__ void edge_exp_kernel(const int* __restrict__ dst, float* __restrict__ logit,
                                const float* __restrict__ segmax, float* __restrict__ denom,
                                int E) {
    int e = blockIdx.x * blockDim.x + threadIdx.x;
    if (e >= E) return;
    int d = dst[e];
    float ex = expf(logit[e] - segmax[d]);
    logit[e] = ex;
    atomicAdd(&denom[d], ex);
}

// ---------------------------------------------------------------------------
// Pass 3: out[dst] += (ex/(denom[dst]+eps)) * hs[src]   one lane per (edge,feature)
// 64 lanes of a wave = one edge -> src/dst/ex/denom loads are wave-broadcast.
// ---------------------------------------------------------------------------
__global__ void edge_aggregate_kernel(const int* __restrict__ src, const int* __restrict__ dst,
                                      const float* __restrict__ ex, const float* __restrict__ denom,
                                      const float* __restrict__ hs, float* __restrict__ out,
                                      int total) {
    int i = blockIdx.x * blockDim.x + threadIdx.x;
    if (i >= total) return;
    int e = i >> 6, j = i & 63;
    int s = src[e], d = dst[e];
    float alpha = ex[e] / (denom[d] + EPS_F);
    atomicAdd(&out[(size_t)d * HDIM + j], alpha * hs[(size_t)s * HDIM + j]);
}

// ---------------------------------------------------------------------------
extern "C" void kernel_launch(void* const* d_in, const int* in_sizes, int n_in,
                              void* d_out, int out_size, void* d_ws, size_t ws_size,
                              hipStream_t stream) {
    const float* x = (const float*)d_in[0];
    const int* ei = (const int*)d_in[1];
    const int E = in_sizes[1] / 2;
    const int din1 = in_sizes[2] / HDIM;  // 128
    const int N = in_sizes[0] / din1;     // 100000
    const int* src = ei;
    const int* dst = ei + E;

    // params per layer: Ws, Wd, a_s, a_d, b  at d_in[2+5*l ...]
    const float* P[15];
    for (int i = 0; i < 15; ++i) P[i] = (const float*)d_in[2 + i];

    // workspace carve-up (floats)
    // Layers ping-pong between xb (ws) and d_out:
    //   L1: x   -> xb ;  L2: xb -> d_out ;  L3: d_out -> d_out
    // (xin is consumed by the GEMM before init_layer overwrites xout, so
    //  xin == xout is safe within the stream ordering.)
    float* w = (float*)d_ws;
    float* hs = w;      w += (size_t)N * HDIM;
    float* xb = w;      w += (size_t)N * HDIM;
    float* als = w;     w += N;
    float* ald = w;     w += N;
    float* segmax = w;  w += N;
    float* denom = w;   w += N;
    float* vd = w;      w += 128;
    float* logit = w;   w += E;

    const int BT = 256;
    const int gridN32 = (N + 31) / 32;
    const int gridNH = (N * HDIM + BT - 1) / BT;
    const int gridE = (E + BT - 1) / BT;
    const int gridEH = (E * HDIM + BT - 1) / BT;

    auto run_layer = [&](const float* xin, int din, const float* Ws, const float* Wd,
                         const float* as_, const float* ad_, const float* b, float* xout) {
        compute_vd_kernel<<<1, 128, 0, stream>>>(Wd, ad_, vd, din);
        if (din == 128)
            gemm_fused_kernel<128><<<gridN32, BT, 0, stream>>>(xin, Ws, as_, vd, hs, als, ald, N);
        else
            gemm_fused_kernel<64><<<gridN32, BT, 0, stream>>>(xin, Ws, as_, vd, hs, als, ald, N);
        init_layer_kernel<<<gridNH, BT, 0, stream>>>(xout, b, segmax, denom, N);
        edge_logit_kernel<<<gridE, BT, 0, stream>>>(src, dst, als, ald, logit, segmax, E);
        edge_exp_kernel<<<gridE, BT, 0, stream>>>(dst, logit, segmax, denom, E);
        edge_aggregate_kernel<<<gridEH, BT, 0, stream>>>(src, dst, logit, denom, hs, xout,
                                                         E * HDIM);
    };

    float* out = (float*)d_out;
    run_layer(x,   din1, P[0],  P[1],  P[2],  P[3],  P[4],  xb);
    run_layer(xb,  HDIM, P[5],  P[6],  P[7],  P[8],  P[9],  out);
    run_layer(out, HDIM, P[10], P[11], P[12], P[13], P[14], out);
}

// Round 4
// 884.195 us; speedup vs baseline: 1.9864x; 1.9864x over previous
//
#include <hip/hip_runtime.h>

#define HDIM 64
#define EPS_F 1e-16f
#define SCHUNK 1024

// ---------------------------------------------------------------------------
// vd[k] = sum_j Wd[k][j] * a_d[j]
// ---------------------------------------------------------------------------
__global__ void compute_vd_kernel(const float* __restrict__ Wd,
                                  const float* __restrict__ ad,
                                  float* __restrict__ vd, int din) {
    int k = blockIdx.x * blockDim.x + threadIdx.x;
    if (k >= din) return;
    float s = 0.f;
#pragma unroll
    for (int j = 0; j < HDIM; ++j) s = fmaf(Wd[k * HDIM + j], ad[j], s);
    vd[k] = s;
}

// ---------------------------------------------------------------------------
// Fused: hs = x @ Ws ;  als = hs . a_s ;  ald = x . vd
// ---------------------------------------------------------------------------
template <int DIN>
__global__ __launch_bounds__(256) void gemm_fused_kernel(
    const float* __restrict__ xin, const float* __restrict__ Ws,
    const float* __restrict__ as_, const float* __restrict__ vd,
    float* __restrict__ hs, float* __restrict__ als, float* __restrict__ ald,
    int N) {
    __shared__ float wsh[DIN * HDIM];
    __shared__ float xs[32 * (DIN + 4)];
    __shared__ float ash[HDIM];
    __shared__ float vdsh[DIN];

    const int tid = threadIdx.x;
    const int n0 = blockIdx.x * 32;

    for (int i = tid * 4; i < DIN * HDIM; i += 256 * 4)
        *(float4*)&wsh[i] = *(const float4*)&Ws[i];
    if (tid < HDIM) ash[tid] = as_[tid];
    if (tid < DIN) vdsh[tid] = vd[tid];
    for (int i = tid; i < 32 * DIN / 4; i += 256) {
        int idx = i * 4;
        int n = idx / DIN, k = idx - n * DIN;
        float4 v = make_float4(0.f, 0.f, 0.f, 0.f);
        if (n0 + n < N) v = *(const float4*)&xin[(size_t)(n0 + n) * DIN + k];
        *(float4*)&xs[n * (DIN + 4) + k] = v;
    }
    __syncthreads();

    const int nl = tid >> 3, jg = tid & 7, j0 = jg * 8;
    const int n = n0 + nl;
    float acc[8] = {0.f, 0.f, 0.f, 0.f, 0.f, 0.f, 0.f, 0.f};
    float aldp = 0.f;
    const float* xrow = &xs[nl * (DIN + 4)];
#pragma unroll 4
    for (int k = 0; k < DIN; ++k) {
        float xv = xrow[k];
        aldp = fmaf(xv, vdsh[k], aldp);
        float4 w0 = *(const float4*)&wsh[k * HDIM + j0];
        float4 w1 = *(const float4*)&wsh[k * HDIM + j0 + 4];
        acc[0] = fmaf(xv, w0.x, acc[0]);
        acc[1] = fmaf(xv, w0.y, acc[1]);
        acc[2] = fmaf(xv, w0.z, acc[2]);
        acc[3] = fmaf(xv, w0.w, acc[3]);
        acc[4] = fmaf(xv, w1.x, acc[4]);
        acc[5] = fmaf(xv, w1.y, acc[5]);
        acc[6] = fmaf(xv, w1.z, acc[6]);
        acc[7] = fmaf(xv, w1.w, acc[7]);
    }
    float alsp = 0.f;
#pragma unroll
    for (int jj = 0; jj < 8; ++jj) alsp = fmaf(acc[jj], ash[j0 + jj], alsp);
    alsp += __shfl_down(alsp, 4, 8);
    alsp += __shfl_down(alsp, 2, 8);
    alsp += __shfl_down(alsp, 1, 8);

    if (n < N) {
        *(float4*)&hs[(size_t)n * HDIM + j0] =
            make_float4(acc[0], acc[1], acc[2], acc[3]);
        *(float4*)&hs[(size_t)n * HDIM + j0 + 4] =
            make_float4(acc[4], acc[5], acc[6], acc[7]);
        if (jg == 0) {
            als[n] = alsp;
            ald[n] = aldp;
        }
    }
}

// ---------------------------------------------------------------------------
// CSR build: zero, histogram, 3-phase exclusive scan, scatter
// ---------------------------------------------------------------------------
__global__ void zero_kernel(int* __restrict__ p, int n) {
    int i = blockIdx.x * blockDim.x + threadIdx.x;
    if (i < n) p[i] = 0;
}

__global__ void hist_kernel(const int* __restrict__ dst, int* __restrict__ deg, int E) {
    int e = blockIdx.x * blockDim.x + threadIdx.x;
    if (e < E) atomicAdd(&deg[dst[e]], 1);
}

__global__ __launch_bounds__(256) void scan1_kernel(const int* __restrict__ deg,
                                                    int* __restrict__ blocksums, int N) {
    __shared__ int red[256];
    int b = blockIdx.x, t = threadIdx.x;
    int i0 = b * SCHUNK + t * 4;
    int s = 0;
#pragma unroll
    for (int j = 0; j < 4; ++j) {
        int i = i0 + j;
        if (i < N) s += deg[i];
    }
    red[t] = s;
    __syncthreads();
    for (int off = 128; off; off >>= 1) {
        if (t < off) red[t] += red[t + off];
        __syncthreads();
    }
    if (t == 0) blocksums[b] = red[0];
}

__global__ __launch_bounds__(256) void scan2_kernel(const int* __restrict__ blocksums,
                                                    int* __restrict__ blockoffs, int nb) {
    __shared__ int tmp[256];
    int t = threadIdx.x;
    tmp[t] = (t < nb) ? blocksums[t] : 0;
    __syncthreads();
    for (int off = 1; off < 256; off <<= 1) {
        int add = (t >= off) ? tmp[t - off] : 0;
        __syncthreads();
        tmp[t] += add;
        __syncthreads();
    }
    if (t < nb) blockoffs[t] = (t == 0) ? 0 : tmp[t - 1];
}

__global__ __launch_bounds__(256) void scan3_kernel(const int* __restrict__ deg,
                                                    const int* __restrict__ blockoffs,
                                                    int* __restrict__ rowptr,
                                                    int* __restrict__ cursor, int N) {
    __shared__ int ts[256];
    int b = blockIdx.x, t = threadIdx.x;
    int i0 = b * SCHUNK + t * 4;
    int v[4], s = 0;
#pragma unroll
    for (int j = 0; j < 4; ++j) {
        int i = i0 + j;
        v[j] = (i < N) ? deg[i] : 0;
        s += v[j];
    }
    ts[t] = s;
    __syncthreads();
    for (int off = 1; off < 256; off <<= 1) {
        int add = (t >= off) ? ts[t - off] : 0;
        __syncthreads();
        ts[t] += add;
        __syncthreads();
    }
    int run = (t == 0 ? 0 : ts[t - 1]) + blockoffs[b];
#pragma unroll
    for (int j = 0; j < 4; ++j) {
        int i = i0 + j;
        if (i <= N) {
            rowptr[i] = run;
            cursor[i] = run;
        }
        run += v[j];
    }
}

__global__ void scatter_kernel(const int* __restrict__ src, const int* __restrict__ dst,
                               int* __restrict__ cursor, int* __restrict__ csr_src, int E) {
    int e = blockIdx.x * blockDim.x + threadIdx.x;
    if (e >= E) return;
    int pos = atomicAdd(&cursor[dst[e]], 1);
    csr_src[pos] = src[e];
}

// ---------------------------------------------------------------------------
// Fused sparse layer: one wave per dst node, lane = feature.
// Phase A: edge-parallel segment max of relu(als[src]+ald[d]) (init 0 valid).
// Phase B: serial edge loop; coalesced 256B gather of hs[src]; register acc.
// ---------------------------------------------------------------------------
__global__ __launch_bounds__(256) void gat_sparse_kernel(
    const int* __restrict__ rowptr, const int* __restrict__ csr_src,
    const float* __restrict__ als, const float* __restrict__ ald,
    const float* __restrict__ hs, const float* __restrict__ b,
    float* __restrict__ out, int N) {
    int wid = (blockIdx.x * 256 + threadIdx.x) >> 6;  // node id
    int lane = threadIdx.x & 63;
    if (wid >= N) return;
    int start = rowptr[wid], end = rowptr[wid + 1];
    float aldd = ald[wid];

    // phase A: max over relu'd logits (>=0, so init 0)
    float m = 0.f;
    for (int k = start + lane; k < end; k += 64) {
        int s = csr_src[k];
        m = fmaxf(m, als[s] + aldd);
    }
#pragma unroll
    for (int off = 32; off; off >>= 1) m = fmaxf(m, __shfl_xor(m, off));

    // phase B: exp + weighted accumulation
    float acc = 0.f, denom = 0.f;
    for (int k = start; k < end; ++k) {
        int s = csr_src[k];
        float l = als[s] + aldd;
        l = l > 0.f ? l : 0.f;
        float ex = __expf(l - m);
        denom += ex;
        acc = fmaf(ex, hs[(size_t)s * HDIM + lane], acc);
    }
    out[(size_t)wid * HDIM + lane] = acc / (denom + EPS_F) + b[lane];
}

// ---------------------------------------------------------------------------
extern "C" void kernel_launch(void* const* d_in, const int* in_sizes, int n_in,
                              void* d_out, int out_size, void* d_ws, size_t ws_size,
                              hipStream_t stream) {
    const float* x = (const float*)d_in[0];
    const int* ei = (const int*)d_in[1];
    const int E = in_sizes[1] / 2;
    const int din1 = in_sizes[2] / HDIM;  // 128
    const int N = in_sizes[0] / din1;     // 100000
    const int* src = ei;
    const int* dst = ei + E;

    const float* P[15];
    for (int i = 0; i < 15; ++i) P[i] = (const float*)d_in[2 + i];

    // workspace carve-up (4-byte units); float4-loaded arrays kept 16B-aligned
    float* w = (float*)d_ws;
    float* hs = w;      w += (size_t)N * HDIM;
    float* xb = w;      w += (size_t)N * HDIM;
    float* als = w;     w += N;
    float* ald = w;     w += N;
    float* vd = w;      w += 128;
    int* ip = (int*)w;
    int* deg = ip;        ip += N;
    int* rowptr = ip;     ip += N + 1;
    int* cursor = ip;     ip += N + 1;
    int* blocksums = ip;  ip += 256;
    int* blockoffs = ip;  ip += 256;
    int* csr_src = ip;    ip += E;

    const int BT = 256;
    const int gridN32 = (N + 31) / 32;
    const int gridE = (E + BT - 1) / BT;
    const int gridN = (N + BT - 1) / BT;
    const int nScanBlocks = (N + SCHUNK - 1) / SCHUNK;  // 98
    const int gridSparse = (N * 64 + BT - 1) / BT;      // 1 wave per node

    // ---- CSR build (once; same edge_index for all 3 layers) ----
    zero_kernel<<<gridN, BT, 0, stream>>>(deg, N);
    hist_kernel<<<gridE, BT, 0, stream>>>(dst, deg, E);
    scan1_kernel<<<nScanBlocks, BT, 0, stream>>>(deg, blocksums, N);
    scan2_kernel<<<1, BT, 0, stream>>>(blocksums, blockoffs, nScanBlocks);
    scan3_kernel<<<nScanBlocks, BT, 0, stream>>>(deg, blockoffs, rowptr, cursor, N);
    scatter_kernel<<<gridE, BT, 0, stream>>>(src, dst, cursor, csr_src, E);

    auto run_layer = [&](const float* xin, int din, const float* Ws, const float* Wd,
                         const float* as_, const float* ad_, const float* b, float* xout) {
        compute_vd_kernel<<<1, 128, 0, stream>>>(Wd, ad_, vd, din);
        if (din == 128)
            gemm_fused_kernel<128><<<gridN32, BT, 0, stream>>>(xin, Ws, as_, vd, hs, als, ald, N);
        else
            gemm_fused_kernel<64><<<gridN32, BT, 0, stream>>>(xin, Ws, as_, vd, hs, als, ald, N);
        gat_sparse_kernel<<<gridSparse, BT, 0, stream>>>(rowptr, csr_src, als, ald, hs, b,
                                                         xout, N);
    };

    float* out = (float*)d_out;
    run_layer(x,   din1, P[0],  P[1],  P[2],  P[3],  P[4],  xb);
    run_layer(xb,  HDIM, P[5],  P[6],  P[7],  P[8],  P[9],  out);
    run_layer(out, HDIM, P[10], P[11], P[12], P[13], P[14], out);
}

// Round 5
// 635.338 us; speedup vs baseline: 2.7645x; 1.3917x over previous
//
#include <hip/hip_runtime.h>

#define HDIM 64
#define EPS_F 1e-16f
#define SCHUNK 1024

// ---------------------------------------------------------------------------
// vd[k] = sum_j Wd[k][j] * a_d[j]
// ---------------------------------------------------------------------------
__global__ void compute_vd_kernel(const float* __restrict__ Wd,
                                  const float* __restrict__ ad,
                                  float* __restrict__ vd, int din) {
    int k = blockIdx.x * blockDim.x + threadIdx.x;
    if (k >= din) return;
    float s = 0.f;
#pragma unroll
    for (int j = 0; j < HDIM; ++j) s = fmaf(Wd[k * HDIM + j], ad[j], s);
    vd[k] = s;
}

// ---------------------------------------------------------------------------
// Fused: hs = x @ Ws ;  als = hs . a_s ;  ald = x . vd
// ---------------------------------------------------------------------------
template <int DIN>
__global__ __launch_bounds__(256) void gemm_fused_kernel(
    const float* __restrict__ xin, const float* __restrict__ Ws,
    const float* __restrict__ as_, const float* __restrict__ vd,
    float* __restrict__ hs, float* __restrict__ als, float* __restrict__ ald,
    int N) {
    __shared__ float wsh[DIN * HDIM];
    __shared__ float xs[32 * (DIN + 4)];
    __shared__ float ash[HDIM];
    __shared__ float vdsh[DIN];

    const int tid = threadIdx.x;
    const int n0 = blockIdx.x * 32;

    for (int i = tid * 4; i < DIN * HDIM; i += 256 * 4)
        *(float4*)&wsh[i] = *(const float4*)&Ws[i];
    if (tid < HDIM) ash[tid] = as_[tid];
    if (tid < DIN) vdsh[tid] = vd[tid];
    for (int i = tid; i < 32 * DIN / 4; i += 256) {
        int idx = i * 4;
        int n = idx / DIN, k = idx - n * DIN;
        float4 v = make_float4(0.f, 0.f, 0.f, 0.f);
        if (n0 + n < N) v = *(const float4*)&xin[(size_t)(n0 + n) * DIN + k];
        *(float4*)&xs[n * (DIN + 4) + k] = v;
    }
    __syncthreads();

    const int nl = tid >> 3, jg = tid & 7, j0 = jg * 8;
    const int n = n0 + nl;
    float acc[8] = {0.f, 0.f, 0.f, 0.f, 0.f, 0.f, 0.f, 0.f};
    float aldp = 0.f;
    const float* xrow = &xs[nl * (DIN + 4)];
#pragma unroll 4
    for (int k = 0; k < DIN; ++k) {
        float xv = xrow[k];
        aldp = fmaf(xv, vdsh[k], aldp);
        float4 w0 = *(const float4*)&wsh[k * HDIM + j0];
        float4 w1 = *(const float4*)&wsh[k * HDIM + j0 + 4];
        acc[0] = fmaf(xv, w0.x, acc[0]);
        acc[1] = fmaf(xv, w0.y, acc[1]);
        acc[2] = fmaf(xv, w0.z, acc[2]);
        acc[3] = fmaf(xv, w0.w, acc[3]);
        acc[4] = fmaf(xv, w1.x, acc[4]);
        acc[5] = fmaf(xv, w1.y, acc[5]);
        acc[6] = fmaf(xv, w1.z, acc[6]);
        acc[7] = fmaf(xv, w1.w, acc[7]);
    }
    float alsp = 0.f;
#pragma unroll
    for (int jj = 0; jj < 8; ++jj) alsp = fmaf(acc[jj], ash[j0 + jj], alsp);
    alsp += __shfl_down(alsp, 4, 8);
    alsp += __shfl_down(alsp, 2, 8);
    alsp += __shfl_down(alsp, 1, 8);

    if (n < N) {
        *(float4*)&hs[(size_t)n * HDIM + j0] =
            make_float4(acc[0], acc[1], acc[2], acc[3]);
        *(float4*)&hs[(size_t)n * HDIM + j0 + 4] =
            make_float4(acc[4], acc[5], acc[6], acc[7]);
        if (jg == 0) {
            als[n] = alsp;
            ald[n] = aldp;
        }
    }
}

// ---------------------------------------------------------------------------
// CSR build: zero, histogram, 3-phase exclusive scan, scatter
// ---------------------------------------------------------------------------
__global__ void zero_kernel(int* __restrict__ p, int n) {
    int i = blockIdx.x * blockDim.x + threadIdx.x;
    if (i < n) p[i] = 0;
}

__global__ void hist_kernel(const int* __restrict__ dst, int* __restrict__ deg, int E) {
    int e = blockIdx.x * blockDim.x + threadIdx.x;
    if (e < E) atomicAdd(&deg[dst[e]], 1);
}

__global__ __launch_bounds__(256) void scan1_kernel(const int* __restrict__ deg,
                                                    int* __restrict__ blocksums, int N) {
    __shared__ int red[256];
    int b = blockIdx.x, t = threadIdx.x;
    int i0 = b * SCHUNK + t * 4;
    int s = 0;
#pragma unroll
    for (int j = 0; j < 4; ++j) {
        int i = i0 + j;
        if (i < N) s += deg[i];
    }
    red[t] = s;
    __syncthreads();
    for (int off = 128; off; off >>= 1) {
        if (t < off) red[t] += red[t + off];
        __syncthreads();
    }
    if (t == 0) blocksums[b] = red[0];
}

__global__ __launch_bounds__(256) void scan2_kernel(const int* __restrict__ blocksums,
                                                    int* __restrict__ blockoffs, int nb) {
    __shared__ int tmp[256];
    int t = threadIdx.x;
    tmp[t] = (t < nb) ? blocksums[t] : 0;
    __syncthreads();
    for (int off = 1; off < 256; off <<= 1) {
        int add = (t >= off) ? tmp[t - off] : 0;
        __syncthreads();
        tmp[t] += add;
        __syncthreads();
    }
    if (t < nb) blockoffs[t] = (t == 0) ? 0 : tmp[t - 1];
}

__global__ __launch_bounds__(256) void scan3_kernel(const int* __restrict__ deg,
                                                    const int* __restrict__ blockoffs,
                                                    int* __restrict__ rowptr,
                                                    int* __restrict__ cursor, int N) {
    __shared__ int ts[256];
    int b = blockIdx.x, t = threadIdx.x;
    int i0 = b * SCHUNK + t * 4;
    int v[4], s = 0;
#pragma unroll
    for (int j = 0; j < 4; ++j) {
        int i = i0 + j;
        v[j] = (i < N) ? deg[i] : 0;
        s += v[j];
    }
    ts[t] = s;
    __syncthreads();
    for (int off = 1; off < 256; off <<= 1) {
        int add = (t >= off) ? ts[t - off] : 0;
        __syncthreads();
        ts[t] += add;
        __syncthreads();
    }
    int run = (t == 0 ? 0 : ts[t - 1]) + blockoffs[b];
#pragma unroll
    for (int j = 0; j < 4; ++j) {
        int i = i0 + j;
        if (i <= N) {
            rowptr[i] = run;
            cursor[i] = run;
        }
        run += v[j];
    }
}

__global__ void scatter_kernel(const int* __restrict__ src, const int* __restrict__ dst,
                               int* __restrict__ cursor, int* __restrict__ csr_src, int E) {
    int e = blockIdx.x * blockDim.x + threadIdx.x;
    if (e >= E) return;
    int pos = atomicAdd(&cursor[dst[e]], 1);
    csr_src[pos] = src[e];
}

// ---------------------------------------------------------------------------
// Fused sparse layer: one wave per dst node.
// Phase A: edge-parallel (lane=edge) segment max of relu(als[src]+ald[d]).
// Phase B: 4 edges/iter (16 lanes/edge, float4/lane) x2 unrolled -> 8 row
//          gathers in flight per wave; cross-lane reduce at the end.
// ---------------------------------------------------------------------------
__global__ __launch_bounds__(256) void gat_sparse_kernel(
    const int* __restrict__ rowptr, const int* __restrict__ csr_src,
    const float* __restrict__ als, const float* __restrict__ ald,
    const float* __restrict__ hs, const float* __restrict__ b,
    float* __restrict__ out, int N) {
    int wid = (blockIdx.x * 256 + threadIdx.x) >> 6;  // node id
    int lane = threadIdx.x & 63;
    if (wid >= N) return;
    int start = rowptr[wid], end = rowptr[wid + 1];
    float aldd = ald[wid];

    // phase A: max over relu'd logits (>=0, so init 0)
    float m = 0.f;
    for (int k = start + lane; k < end; k += 64)
        m = fmaxf(m, als[csr_src[k]] + aldd);
#pragma unroll
    for (int off = 32; off; off >>= 1) m = fmaxf(m, __shfl_xor(m, off));

    // phase B
    const int esub = lane >> 4, fg = lane & 15;
    float4 acc = make_float4(0.f, 0.f, 0.f, 0.f);
    float denom = 0.f;
    for (int k0 = start; k0 < end; k0 += 8) {
        int ka = k0 + esub, kb = k0 + 4 + esub;
        float exa = 0.f, exb = 0.f;
        float4 ha = make_float4(0.f, 0.f, 0.f, 0.f);
        float4 hb = make_float4(0.f, 0.f, 0.f, 0.f);
        if (ka < end) {
            int s = csr_src[ka];
            float l = als[s] + aldd;
            l = l > 0.f ? l : 0.f;
            exa = __expf(l - m);
            ha = *(const float4*)&hs[(size_t)s * HDIM + fg * 4];
        }
        if (kb < end) {
            int s = csr_src[kb];
            float l = als[s] + aldd;
            l = l > 0.f ? l : 0.f;
            exb = __expf(l - m);
            hb = *(const float4*)&hs[(size_t)s * HDIM + fg * 4];
        }
        denom += exa + exb;
        acc.x = fmaf(exa, ha.x, acc.x);
        acc.y = fmaf(exa, ha.y, acc.y);
        acc.z = fmaf(exa, ha.z, acc.z);
        acc.w = fmaf(exa, ha.w, acc.w);
        acc.x = fmaf(exb, hb.x, acc.x);
        acc.y = fmaf(exb, hb.y, acc.y);
        acc.z = fmaf(exb, hb.z, acc.z);
        acc.w = fmaf(exb, hb.w, acc.w);
    }
    // reduce across the 4 edge-subgroups (lanes differing in bits 4,5)
#pragma unroll
    for (int off = 16; off < 64; off <<= 1) {
        acc.x += __shfl_xor(acc.x, off);
        acc.y += __shfl_xor(acc.y, off);
        acc.z += __shfl_xor(acc.z, off);
        acc.w += __shfl_xor(acc.w, off);
        denom += __shfl_xor(denom, off);
    }
    if (esub == 0) {
        float inv = 1.f / (denom + EPS_F);
        const float4 b4 = *(const float4*)&b[fg * 4];
        float4 o;
        o.x = acc.x * inv + b4.x;
        o.y = acc.y * inv + b4.y;
        o.z = acc.z * inv + b4.z;
        o.w = acc.w * inv + b4.w;
        *(float4*)&out[(size_t)wid * HDIM + fg * 4] = o;
    }
}

// ---------------------------------------------------------------------------
extern "C" void kernel_launch(void* const* d_in, const int* in_sizes, int n_in,
                              void* d_out, int out_size, void* d_ws, size_t ws_size,
                              hipStream_t stream) {
    const float* x = (const float*)d_in[0];
    const int* ei = (const int*)d_in[1];
    const int E = in_sizes[1] / 2;
    const int din1 = in_sizes[2] / HDIM;  // 128
    const int N = in_sizes[0] / din1;     // 100000
    const int* src = ei;
    const int* dst = ei + E;

    const float* P[15];
    for (int i = 0; i < 15; ++i) P[i] = (const float*)d_in[2 + i];

    // workspace carve-up (4-byte units); float4-loaded arrays kept 16B-aligned
    float* w = (float*)d_ws;
    float* hs = w;      w += (size_t)N * HDIM;
    float* xb = w;      w += (size_t)N * HDIM;
    float* als = w;     w += N;
    float* ald = w;     w += N;
    float* vd = w;      w += 128;
    int* ip = (int*)w;
    int* deg = ip;        ip += N;
    int* rowptr = ip;     ip += N + 1;
    int* cursor = ip;     ip += N + 1;
    int* blocksums = ip;  ip += 256;
    int* blockoffs = ip;  ip += 256;
    int* csr_src = ip;    ip += E;

    const int BT = 256;
    const int gridN32 = (N + 31) / 32;
    const int gridE = (E + BT - 1) / BT;
    const int gridN = (N + BT - 1) / BT;
    const int nScanBlocks = (N + SCHUNK - 1) / SCHUNK;  // 98
    const int gridSparse = (N * 64 + BT - 1) / BT;      // 1 wave per node

    // ---- CSR build (once; same edge_index for all 3 layers) ----
    zero_kernel<<<gridN, BT, 0, stream>>>(deg, N);
    hist_kernel<<<gridE, BT, 0, stream>>>(dst, deg, E);
    scan1_kernel<<<nScanBlocks, BT, 0, stream>>>(deg, blocksums, N);
    scan2_kernel<<<1, BT, 0, stream>>>(blocksums, blockoffs, nScanBlocks);
    scan3_kernel<<<nScanBlocks, BT, 0, stream>>>(deg, blockoffs, rowptr, cursor, N);
    scatter_kernel<<<gridE, BT, 0, stream>>>(src, dst, cursor, csr_src, E);

    auto run_layer = [&](const float* xin, int din, const float* Ws, const float* Wd,
                         const float* as_, const float* ad_, const float* b, float* xout) {
        compute_vd_kernel<<<1, 128, 0, stream>>>(Wd, ad_, vd, din);
        if (din == 128)
            gemm_fused_kernel<128><<<gridN32, BT, 0, stream>>>(xin, Ws, as_, vd, hs, als, ald, N);
        else
            gemm_fused_kernel<64><<<gridN32, BT, 0, stream>>>(xin, Ws, as_, vd, hs, als, ald, N);
        gat_sparse_kernel<<<gridSparse, BT, 0, stream>>>(rowptr, csr_src, als, ald, hs, b,
                                                         xout, N);
    };

    float* out = (float*)d_out;
    run_layer(x,   din1, P[0],  P[1],  P[2],  P[3],  P[4],  xb);
    run_layer(xb,  HDIM, P[5],  P[6],  P[7],  P[8],  P[9],  out);
    run_layer(out, HDIM, P[10], P[11], P[12], P[13], P[14], out);
}

// Round 7
// 490.683 us; speedup vs baseline: 3.5795x; 1.2948x over previous
//
#include <hip/hip_runtime.h>
#include <hip/hip_fp16.h>

#define HDIM 64
#define EPS_F 1e-16f
#define CH 8192          // edges per block in binning/hist passes
#define BSH 9            // bucket shift: 512 nodes per bucket

// ---------------------------------------------------------------------------
// vd[k] = sum_j Wd[k][j] * a_d[j]
// ---------------------------------------------------------------------------
__global__ void compute_vd_kernel(const float* __restrict__ Wd,
                                  const float* __restrict__ ad,
                                  float* __restrict__ vd, int din) {
    int k = blockIdx.x * blockDim.x + threadIdx.x;
    if (k >= din) return;
    float s = 0.f;
#pragma unroll
    for (int j = 0; j < HDIM; ++j) s = fmaf(Wd[k * HDIM + j], ad[j], s);
    vd[k] = s;
}

// ---------------------------------------------------------------------------
// Fused: hs = x @ Ws (stored fp16) ;  als = hs . a_s (f32) ;  ald = x . vd
// ---------------------------------------------------------------------------
template <int DIN>
__global__ __launch_bounds__(256) void gemm_fused_kernel(
    const float* __restrict__ xin, const float* __restrict__ Ws,
    const float* __restrict__ as_, const float* __restrict__ vd,
    __half* __restrict__ hs, float* __restrict__ als, float* __restrict__ ald,
    int N) {
    __shared__ float wsh[DIN * HDIM];
    __shared__ float xs[32 * (DIN + 4)];
    __shared__ float ash[HDIM];
    __shared__ float vdsh[DIN];

    const int tid = threadIdx.x;
    const int n0 = blockIdx.x * 32;

    for (int i = tid * 4; i < DIN * HDIM; i += 256 * 4)
        *(float4*)&wsh[i] = *(const float4*)&Ws[i];
    if (tid < HDIM) ash[tid] = as_[tid];
    if (tid < DIN) vdsh[tid] = vd[tid];
    for (int i = tid; i < 32 * DIN / 4; i += 256) {
        int idx = i * 4;
        int n = idx / DIN, k = idx - n * DIN;
        float4 v = make_float4(0.f, 0.f, 0.f, 0.f);
        if (n0 + n < N) v = *(const float4*)&xin[(size_t)(n0 + n) * DIN + k];
        *(float4*)&xs[n * (DIN + 4) + k] = v;
    }
    __syncthreads();

    const int nl = tid >> 3, jg = tid & 7, j0 = jg * 8;
    const int n = n0 + nl;
    float acc[8] = {0.f, 0.f, 0.f, 0.f, 0.f, 0.f, 0.f, 0.f};
    float aldp = 0.f;
    const float* xrow = &xs[nl * (DIN + 4)];
#pragma unroll 4
    for (int k = 0; k < DIN; ++k) {
        float xv = xrow[k];
        aldp = fmaf(xv, vdsh[k], aldp);
        float4 w0 = *(const float4*)&wsh[k * HDIM + j0];
        float4 w1 = *(const float4*)&wsh[k * HDIM + j0 + 4];
        acc[0] = fmaf(xv, w0.x, acc[0]);
        acc[1] = fmaf(xv, w0.y, acc[1]);
        acc[2] = fmaf(xv, w0.z, acc[2]);
        acc[3] = fmaf(xv, w0.w, acc[3]);
        acc[4] = fmaf(xv, w1.x, acc[4]);
        acc[5] = fmaf(xv, w1.y, acc[5]);
        acc[6] = fmaf(xv, w1.z, acc[6]);
        acc[7] = fmaf(xv, w1.w, acc[7]);
    }
    float alsp = 0.f;
#pragma unroll
    for (int jj = 0; jj < 8; ++jj) alsp = fmaf(acc[jj], ash[j0 + jj], alsp);
    alsp += __shfl_down(alsp, 4, 8);
    alsp += __shfl_down(alsp, 2, 8);
    alsp += __shfl_down(alsp, 1, 8);

    if (n < N) {
        union { __half h[8]; float4 f; } u;
#pragma unroll
        for (int jj = 0; jj < 8; ++jj) u.h[jj] = __float2half_rn(acc[jj]);
        *(float4*)&hs[(size_t)n * HDIM + j0] = u.f;   // 16B store of 8 halves
        if (jg == 0) {
            als[n] = alsp;
            ald[n] = aldp;
        }
    }
}

// ---------------------------------------------------------------------------
// CSR build, two-level counting sort by dst.
// ---------------------------------------------------------------------------
__global__ void zero_kernel(int* __restrict__ p, int n) {
    int i = blockIdx.x * blockDim.x + threadIdx.x;
    if (i < n) p[i] = 0;
}

// coarse histogram over 196 buckets (dst >> BSH), block-aggregated in LDS
__global__ __launch_bounds__(256) void bucket_hist_kernel(const int* __restrict__ dst,
                                                          int* __restrict__ gbucket, int E) {
    __shared__ int bh[256];
    int t = threadIdx.x;
    bh[t] = 0;
    __syncthreads();
    int e0 = blockIdx.x * CH;
#pragma unroll
    for (int i = 0; i < CH / 256; ++i) {
        int e = e0 + i * 256 + t;
        if (e < E) atomicAdd(&bh[dst[e] >> BSH], 1);
    }
    __syncthreads();
    if (bh[t]) atomicAdd(&gbucket[t], bh[t]);
}

// exclusive scan of bucket counts (nbuk <= 256), one block
__global__ __launch_bounds__(256) void bucket_scan_kernel(const int* __restrict__ gbucket,
                                                          int* __restrict__ bucket_base,
                                                          int* __restrict__ bucket_cur,
                                                          int nbuk, int E) {
    __shared__ int tmp[256];
    int t = threadIdx.x;
    int v = (t < nbuk) ? gbucket[t] : 0;
    tmp[t] = v;
    __syncthreads();
    for (int off = 1; off < 256; off <<= 1) {
        int a = (t >= off) ? tmp[t - off] : 0;
        __syncthreads();
        tmp[t] += a;
        __syncthreads();
    }
    int excl = tmp[t] - v;
    if (t < nbuk) {
        bucket_base[t] = excl;
        bucket_cur[t] = excl;
    }
    if (t == 0) bucket_base[nbuk] = E;
}

// pass A: bin edges into buckets; block-local counts -> one bulk reserve per
// bucket -> writes are contiguous runs per bucket (kills line thrash)
__global__ __launch_bounds__(256) void bin_kernel(const int* __restrict__ src,
                                                  const int* __restrict__ dst,
                                                  int* __restrict__ bucket_cur,
                                                  int2* __restrict__ ebuf, int E) {
    __shared__ int lcnt[256], lbase[256];
    int t = threadIdx.x;
    int e0 = blockIdx.x * CH;
    lcnt[t] = 0;
    __syncthreads();
#pragma unroll
    for (int i = 0; i < CH / 256; ++i) {
        int e = e0 + i * 256 + t;
        if (e < E) atomicAdd(&lcnt[dst[e] >> BSH], 1);
    }
    __syncthreads();
    int c = lcnt[t];
    if (c) lbase[t] = atomicAdd(&bucket_cur[t], c);
    __syncthreads();
    lcnt[t] = 0;
    __syncthreads();
#pragma unroll
    for (int i = 0; i < CH / 256; ++i) {
        int e = e0 + i * 256 + t;
        if (e < E) {
            int d = dst[e];
            int bk = d >> BSH;
            int pos = lbase[bk] + atomicAdd(&lcnt[bk], 1);
            ebuf[pos] = make_int2(src[e], d);
        }
    }
}

// pass B: one block per bucket; LDS counting sort over 512-node range.
// Emits csr_src (contiguous 32KB region per block -> full line utilization)
// and rowptr for the bucket's nodes via the in-LDS exclusive scan.
__global__ __launch_bounds__(256) void bucket_sort_kernel(
    const int2* __restrict__ ebuf, const int* __restrict__ bucket_base,
    int* __restrict__ rowptr, int* __restrict__ csr_src, int N, int E) {
    __shared__ int cnt[512], cur[512], psum[256];
    int b = blockIdx.x, t = threadIdx.x;
    int n0 = b << BSH;
    int nlocal = min(512, N - n0);
    int bstart = bucket_base[b], bend = bucket_base[b + 1];
    cnt[t] = 0;
    cnt[t + 256] = 0;
    __syncthreads();
    for (int k = bstart + t; k < bend; k += 256)
        atomicAdd(&cnt[ebuf[k].y & 511], 1);
    __syncthreads();
    int p = cnt[2 * t] + cnt[2 * t + 1];
    psum[t] = p;
    __syncthreads();
    for (int off = 1; off < 256; off <<= 1) {
        int a = (t >= off) ? psum[t - off] : 0;
        __syncthreads();
        psum[t] += a;
        __syncthreads();
    }
    int excl = psum[t] - p;
    int o0 = excl, o1 = excl + cnt[2 * t];
    cur[2 * t] = o0;
    cur[2 * t + 1] = o1;
    if (2 * t < nlocal) rowptr[n0 + 2 * t] = bstart + o0;
    if (2 * t + 1 < nlocal) rowptr[n0 + 2 * t + 1] = bstart + o1;
    __syncthreads();
    for (int k = bstart + t; k < bend; k += 256) {
        int2 e = ebuf[k];
        int pos = bstart + atomicAdd(&cur[e.y & 511], 1);
        csr_src[pos] = e.x;
    }
    if (b == 0 && t == 0) rowptr[N] = E;
}

// ---------------------------------------------------------------------------
// Fused sparse layer: one wave per dst node.
// Phase A: lane=edge segment max of relu(als[src]+ald[d]).
// Phase B: 4 edges/iter (16 lanes/edge, 4 halves/lane) x2 -> 8 gathers in flight.
// ---------------------------------------------------------------------------
__global__ __launch_bounds__(256) void gat_sparse_kernel(
    const int* __restrict__ rowptr, const int* __restrict__ csr_src,
    const float* __restrict__ als, const float* __restrict__ ald,
    const __half* __restrict__ hs, const float* __restrict__ b,
    float* __restrict__ out, int N) {
    int wid = (blockIdx.x * 256 + threadIdx.x) >> 6;  // node id
    int lane = threadIdx.x & 63;
    if (wid >= N) return;
    int start = rowptr[wid], end = rowptr[wid + 1];
    float aldd = ald[wid];

    // phase A
    float m = 0.f;
    for (int k = start + lane; k < end; k += 64)
        m = fmaxf(m, als[csr_src[k]] + aldd);
#pragma unroll
    for (int off = 32; off; off >>= 1) m = fmaxf(m, __shfl_xor(m, off));

    // phase B
    const int esub = lane >> 4, fg = lane & 15;
    float4 acc = make_float4(0.f, 0.f, 0.f, 0.f);
    float denom = 0.f;
    for (int k0 = start; k0 < end; k0 += 8) {
        int ka = k0 + esub, kb = k0 + 4 + esub;
        float exa = 0.f, exb = 0.f;
        uint2 ra = make_uint2(0u, 0u), rb = make_uint2(0u, 0u);
        if (ka < end) {
            int s = csr_src[ka];
            float l = als[s] + aldd;
            l = l > 0.f ? l : 0.f;
            exa = __expf(l - m);
            ra = *(const uint2*)&hs[(size_t)s * HDIM + fg * 4];
        }
        if (kb < end) {
            int s = csr_src[kb];
            float l = als[s] + aldd;
            l = l > 0.f ? l : 0.f;
            exb = __expf(l - m);
            rb = *(const uint2*)&hs[(size_t)s * HDIM + fg * 4];
        }
        denom += exa + exb;
        float2 fa0 = __half22float2(*(__half2*)&ra.x);
        float2 fa1 = __half22float2(*(__half2*)&ra.y);
        float2 fb0 = __half22float2(*(__half2*)&rb.x);
        float2 fb1 = __half22float2(*(__half2*)&rb.y);
        acc.x = fmaf(exa, fa0.x, acc.x);
        acc.y = fmaf(exa, fa0.y, acc.y);
        acc.z = fmaf(exa, fa1.x, acc.z);
        acc.w = fmaf(exa, fa1.y, acc.w);
        acc.x = fmaf(exb, fb0.x, acc.x);
        acc.y = fmaf(exb, fb0.y, acc.y);
        acc.z = fmaf(exb, fb1.x, acc.z);
        acc.w = fmaf(exb, fb1.y, acc.w);
    }
#pragma unroll
    for (int off = 16; off < 64; off <<= 1) {
        acc.x += __shfl_xor(acc.x, off);
        acc.y += __shfl_xor(acc.y, off);
        acc.z += __shfl_xor(acc.z, off);
        acc.w += __shfl_xor(acc.w, off);
        denom += __shfl_xor(denom, off);
    }
    if (esub == 0) {
        float inv = 1.f / (denom + EPS_F);
        const float4 b4 = *(const float4*)&b[fg * 4];
        float4 o;
        o.x = acc.x * inv + b4.x;
        o.y = acc.y * inv + b4.y;
        o.z = acc.z * inv + b4.z;
        o.w = acc.w * inv + b4.w;
        *(float4*)&out[(size_t)wid * HDIM + fg * 4] = o;
    }
}

// ---------------------------------------------------------------------------
extern "C" void kernel_launch(void* const* d_in, const int* in_sizes, int n_in,
                              void* d_out, int out_size, void* d_ws, size_t ws_size,
                              hipStream_t stream) {
    const float* x = (const float*)d_in[0];
    const int* ei = (const int*)d_in[1];
    const int E = in_sizes[1] / 2;
    const int din1 = in_sizes[2] / HDIM;  // 128
    const int N = in_sizes[0] / din1;     // 100000
    const int* src = ei;
    const int* dst = ei + E;

    const float* P[15];
    for (int i = 0; i < 15; ++i) P[i] = (const float*)d_in[2 + i];

    // workspace carve-up (16B-aligned chunks first)
    float* w = (float*)d_ws;
    __half* hs = (__half*)w;  w += (size_t)N * HDIM / 2;   // N*64 halves
    float* xb = w;            w += (size_t)N * HDIM;
    float* als = w;           w += N;
    float* ald = w;           w += N;
    float* vd = w;            w += 128;
    int* ip = (int*)w;
    int2* ebuf = (int2*)ip;   ip += 2 * (size_t)E;          // (src,dst) pairs
    int* csr_src = ip;        ip += E;
    int* rowptr = ip;         ip += N + 1;
    int* gbucket = ip;        ip += 256;
    int* bucket_base = ip;    ip += 257;
    int* bucket_cur = ip;     ip += 256;

    const int BT = 256;
    const int gridN32 = (N + 31) / 32;
    const int nbuk = (N + 511) >> BSH;               // 196
    const int gridCH = (E + CH - 1) / CH;            // 196
    const int gridSparse = (N * 64 + BT - 1) / BT;   // 1 wave per node

    // ---- CSR build (once; same edge_index for all 3 layers) ----
    zero_kernel<<<1, 256, 0, stream>>>(gbucket, 256);
    bucket_hist_kernel<<<gridCH, BT, 0, stream>>>(dst, gbucket, E);
    bucket_scan_kernel<<<1, BT, 0, stream>>>(gbucket, bucket_base, bucket_cur, nbuk, E);
    bin_kernel<<<gridCH, BT, 0, stream>>>(src, dst, bucket_cur, ebuf, E);
    bucket_sort_kernel<<<nbuk, BT, 0, stream>>>(ebuf, bucket_base, rowptr, csr_src, N, E);

    auto run_layer = [&](const float* xin, int din, const float* Ws, const float* Wd,
                         const float* as_, const float* ad_, const float* b, float* xout) {
        compute_vd_kernel<<<1, 128, 0, stream>>>(Wd, ad_, vd, din);
        if (din == 128)
            gemm_fused_kernel<128><<<gridN32, BT, 0, stream>>>(xin, Ws, as_, vd, hs, als, ald, N);
        else
            gemm_fused_kernel<64><<<gridN32, BT, 0, stream>>>(xin, Ws, as_, vd, hs, als, ald, N);
        gat_sparse_kernel<<<gridSparse, BT, 0, stream>>>(rowptr, csr_src, als, ald, hs, b,
                                                         xout, N);
    };

    float* out = (float*)d_out;
    run_layer(x,   din1, P[0],  P[1],  P[2],  P[3],  P[4],  xb);
    run_layer(xb,  HDIM, P[5],  P[6],  P[7],  P[8],  P[9],  out);
    run_layer(out, HDIM, P[10], P[11], P[12], P[13], P[14], out);
}

// Round 8
// 435.903 us; speedup vs baseline: 4.0294x; 1.1257x over previous
//
#include <hip/hip_runtime.h>
#include <hip/hip_fp16.h>

#define HDIM 64
#define EPS_F 1e-16f
#define CH 8192          // edges per block in binning/hist passes
#define BSH 9            // bucket shift: 512 nodes per bucket

// ---------------------------------------------------------------------------
// vd for all 3 layers in one launch: vd[k] = sum_j Wd[k][j]*a_d[j]
// layout: vd1[0:128), vd2[128:192), vd3[192:256)
// ---------------------------------------------------------------------------
__global__ void compute_vd_all_kernel(const float* __restrict__ Wd1, const float* __restrict__ ad1,
                                      const float* __restrict__ Wd2, const float* __restrict__ ad2,
                                      const float* __restrict__ Wd3, const float* __restrict__ ad3,
                                      float* __restrict__ vd) {
    int l = blockIdx.x;
    int k = threadIdx.x;
    const float* Wd = (l == 0) ? Wd1 : (l == 1) ? Wd2 : Wd3;
    const float* ad = (l == 0) ? ad1 : (l == 1) ? ad2 : ad3;
    int din = (l == 0) ? 128 : 64;
    int off = (l == 0) ? 0 : (l == 1) ? 128 : 192;
    if (k >= din) return;
    float s = 0.f;
#pragma unroll
    for (int j = 0; j < HDIM; ++j) s = fmaf(Wd[k * HDIM + j], ad[j], s);
    vd[off + k] = s;
}

// ---------------------------------------------------------------------------
// Fused: hs = x @ Ws (stored fp16) ;  als = hs . a_s (f32) ;  ald = x . vd
// ---------------------------------------------------------------------------
template <int DIN>
__global__ __launch_bounds__(256) void gemm_fused_kernel(
    const float* __restrict__ xin, const float* __restrict__ Ws,
    const float* __restrict__ as_, const float* __restrict__ vd,
    __half* __restrict__ hs, float* __restrict__ als, float* __restrict__ ald,
    int N) {
    __shared__ float wsh[DIN * HDIM];
    __shared__ float xs[32 * (DIN + 4)];
    __shared__ float ash[HDIM];
    __shared__ float vdsh[DIN];

    const int tid = threadIdx.x;
    const int n0 = blockIdx.x * 32;

    for (int i = tid * 4; i < DIN * HDIM; i += 256 * 4)
        *(float4*)&wsh[i] = *(const float4*)&Ws[i];
    if (tid < HDIM) ash[tid] = as_[tid];
    if (tid < DIN) vdsh[tid] = vd[tid];
    for (int i = tid; i < 32 * DIN / 4; i += 256) {
        int idx = i * 4;
        int n = idx / DIN, k = idx - n * DIN;
        float4 v = make_float4(0.f, 0.f, 0.f, 0.f);
        if (n0 + n < N) v = *(const float4*)&xin[(size_t)(n0 + n) * DIN + k];
        *(float4*)&xs[n * (DIN + 4) + k] = v;
    }
    __syncthreads();

    const int nl = tid >> 3, jg = tid & 7, j0 = jg * 8;
    const int n = n0 + nl;
    float acc[8] = {0.f, 0.f, 0.f, 0.f, 0.f, 0.f, 0.f, 0.f};
    float aldp = 0.f;
    const float* xrow = &xs[nl * (DIN + 4)];
#pragma unroll 4
    for (int k = 0; k < DIN; ++k) {
        float xv = xrow[k];
        aldp = fmaf(xv, vdsh[k], aldp);
        float4 w0 = *(const float4*)&wsh[k * HDIM + j0];
        float4 w1 = *(const float4*)&wsh[k * HDIM + j0 + 4];
        acc[0] = fmaf(xv, w0.x, acc[0]);
        acc[1] = fmaf(xv, w0.y, acc[1]);
        acc[2] = fmaf(xv, w0.z, acc[2]);
        acc[3] = fmaf(xv, w0.w, acc[3]);
        acc[4] = fmaf(xv, w1.x, acc[4]);
        acc[5] = fmaf(xv, w1.y, acc[5]);
        acc[6] = fmaf(xv, w1.z, acc[6]);
        acc[7] = fmaf(xv, w1.w, acc[7]);
    }
    float alsp = 0.f;
#pragma unroll
    for (int jj = 0; jj < 8; ++jj) alsp = fmaf(acc[jj], ash[j0 + jj], alsp);
    alsp += __shfl_down(alsp, 4, 8);
    alsp += __shfl_down(alsp, 2, 8);
    alsp += __shfl_down(alsp, 1, 8);

    if (n < N) {
        union { __half h[8]; float4 f; } u;
#pragma unroll
        for (int jj = 0; jj < 8; ++jj) u.h[jj] = __float2half_rn(acc[jj]);
        *(float4*)&hs[(size_t)n * HDIM + j0] = u.f;   // 16B store of 8 halves
        if (jg == 0) {
            als[n] = alsp;
            ald[n] = aldp;
        }
    }
}

// ---------------------------------------------------------------------------
// CSR build, two-level counting sort by dst.
// ---------------------------------------------------------------------------
__global__ void zero_kernel(int* __restrict__ p, int n) {
    int i = blockIdx.x * blockDim.x + threadIdx.x;
    if (i < n) p[i] = 0;
}

// coarse histogram over buckets (dst >> BSH), block-aggregated in LDS
__global__ __launch_bounds__(256) void bucket_hist_kernel(const int* __restrict__ dst,
                                                          int* __restrict__ gbucket, int E) {
    __shared__ int bh[256];
    int t = threadIdx.x;
    bh[t] = 0;
    __syncthreads();
    int e0 = blockIdx.x * CH;
#pragma unroll
    for (int i = 0; i < CH / 256; ++i) {
        int e = e0 + i * 256 + t;
        if (e < E) atomicAdd(&bh[dst[e] >> BSH], 1);
    }
    __syncthreads();
    if (bh[t]) atomicAdd(&gbucket[t], bh[t]);
}

// exclusive scan of bucket counts (nbuk <= 256), one block
__global__ __launch_bounds__(256) void bucket_scan_kernel(const int* __restrict__ gbucket,
                                                          int* __restrict__ bucket_base,
                                                          int* __restrict__ bucket_cur,
                                                          int nbuk, int E) {
    __shared__ int tmp[256];
    int t = threadIdx.x;
    int v = (t < nbuk) ? gbucket[t] : 0;
    tmp[t] = v;
    __syncthreads();
    for (int off = 1; off < 256; off <<= 1) {
        int a = (t >= off) ? tmp[t - off] : 0;
        __syncthreads();
        tmp[t] += a;
        __syncthreads();
    }
    int excl = tmp[t] - v;
    if (t < nbuk) {
        bucket_base[t] = excl;
        bucket_cur[t] = excl;
    }
    if (t == 0) bucket_base[nbuk] = E;
}

// pass A: bin edges into buckets; block-local counts -> one bulk reserve per
// bucket -> writes are contiguous runs per bucket (kills line thrash)
__global__ __launch_bounds__(256) void bin_kernel(const int* __restrict__ src,
                                                  const int* __restrict__ dst,
                                                  int* __restrict__ bucket_cur,
                                                  int2* __restrict__ ebuf, int E) {
    __shared__ int lcnt[256], lbase[256];
    int t = threadIdx.x;
    int e0 = blockIdx.x * CH;
    lcnt[t] = 0;
    __syncthreads();
#pragma unroll
    for (int i = 0; i < CH / 256; ++i) {
        int e = e0 + i * 256 + t;
        if (e < E) atomicAdd(&lcnt[dst[e] >> BSH], 1);
    }
    __syncthreads();
    int c = lcnt[t];
    if (c) lbase[t] = atomicAdd(&bucket_cur[t], c);
    __syncthreads();
    lcnt[t] = 0;
    __syncthreads();
#pragma unroll
    for (int i = 0; i < CH / 256; ++i) {
        int e = e0 + i * 256 + t;
        if (e < E) {
            int d = dst[e];
            int bk = d >> BSH;
            int pos = lbase[bk] + atomicAdd(&lcnt[bk], 1);
            ebuf[pos] = make_int2(src[e], d);
        }
    }
}

// pass B: one block per bucket; LDS counting sort over 512-node range.
__global__ __launch_bounds__(256) void bucket_sort_kernel(
    const int2* __restrict__ ebuf, const int* __restrict__ bucket_base,
    int* __restrict__ rowptr, int* __restrict__ csr_src, int N, int E) {
    __shared__ int cnt[512], cur[512], psum[256];
    int b = blockIdx.x, t = threadIdx.x;
    int n0 = b << BSH;
    int nlocal = min(512, N - n0);
    int bstart = bucket_base[b], bend = bucket_base[b + 1];
    cnt[t] = 0;
    cnt[t + 256] = 0;
    __syncthreads();
    for (int k = bstart + t; k < bend; k += 256)
        atomicAdd(&cnt[ebuf[k].y & 511], 1);
    __syncthreads();
    int p = cnt[2 * t] + cnt[2 * t + 1];
    psum[t] = p;
    __syncthreads();
    for (int off = 1; off < 256; off <<= 1) {
        int a = (t >= off) ? psum[t - off] : 0;
        __syncthreads();
        psum[t] += a;
        __syncthreads();
    }
    int excl = psum[t] - p;
    int o0 = excl, o1 = excl + cnt[2 * t];
    cur[2 * t] = o0;
    cur[2 * t + 1] = o1;
    if (2 * t < nlocal) rowptr[n0 + 2 * t] = bstart + o0;
    if (2 * t + 1 < nlocal) rowptr[n0 + 2 * t + 1] = bstart + o1;
    __syncthreads();
    for (int k = bstart + t; k < bend; k += 256) {
        int2 e = ebuf[k];
        int pos = bstart + atomicAdd(&cur[e.y & 511], 1);
        csr_src[pos] = e.x;
    }
    if (b == 0 && t == 0) rowptr[N] = E;
}

// ---------------------------------------------------------------------------
// Fused sparse layer: one wave per dst node.
// FAST PATH (deg <= 64, covers ~all nodes at mean degree 16):
//   phase A: lane=edge; keep s, ex=exp(l-m) in registers; shuffle-reduce m,denom.
//   phase B: 8 lanes/edge (uint4 = 8 halves/lane), 16 edges in flight/iter;
//            ex & s fetched by dynamic __shfl (no memory).
// SLOW PATH (deg > 64): previous verified code.
// ---------------------------------------------------------------------------
__global__ __launch_bounds__(256) void gat_sparse_kernel(
    const int* __restrict__ rowptr, const int* __restrict__ csr_src,
    const float* __restrict__ als, const float* __restrict__ ald,
    const __half* __restrict__ hs, const float* __restrict__ b,
    float* __restrict__ out, int N) {
    int wid = (blockIdx.x * 256 + threadIdx.x) >> 6;  // node id
    int lane = threadIdx.x & 63;
    if (wid >= N) return;
    int start = rowptr[wid], end = rowptr[wid + 1];
    int deg = end - start;
    float aldd = ald[wid];

    if (deg <= 64) {
        // ---- fast path ----
        bool valid = lane < deg;
        int s = 0;
        float l = 0.f;
        if (valid) {
            s = csr_src[start + lane];
            float t = als[s] + aldd;
            l = t > 0.f ? t : 0.f;   // relu'd logit >= 0
        }
        float m = l;                  // invalid lanes hold 0 <= any relu'd logit
#pragma unroll
        for (int off = 32; off; off >>= 1) m = fmaxf(m, __shfl_xor(m, off));
        float ex = valid ? __expf(l - m) : 0.f;
        float denom = ex;
#pragma unroll
        for (int off = 32; off; off >>= 1) denom += __shfl_xor(denom, off);

        const int esub = lane >> 3, fg = lane & 7;
        float acc[8] = {0.f, 0.f, 0.f, 0.f, 0.f, 0.f, 0.f, 0.f};
        for (int k0 = 0; k0 < deg; k0 += 16) {
            int ia = k0 + esub, ib = k0 + 8 + esub;      // ia,ib <= 63 always
            float exa = __shfl(ex, ia), exb = __shfl(ex, ib);
            int sa = __shfl(s, ia), sb = __shfl(s, ib);
            bool va = ia < deg, vb = ib < deg;
            uint4 ra, rb;
            if (va) ra = *(const uint4*)&hs[(size_t)sa * HDIM + fg * 8];
            if (vb) rb = *(const uint4*)&hs[(size_t)sb * HDIM + fg * 8];
            if (va) {
                float2 f0 = __half22float2(*(__half2*)&ra.x);
                float2 f1 = __half22float2(*(__half2*)&ra.y);
                float2 f2 = __half22float2(*(__half2*)&ra.z);
                float2 f3 = __half22float2(*(__half2*)&ra.w);
                acc[0] = fmaf(exa, f0.x, acc[0]);
                acc[1] = fmaf(exa, f0.y, acc[1]);
                acc[2] = fmaf(exa, f1.x, acc[2]);
                acc[3] = fmaf(exa, f1.y, acc[3]);
                acc[4] = fmaf(exa, f2.x, acc[4]);
                acc[5] = fmaf(exa, f2.y, acc[5]);
                acc[6] = fmaf(exa, f3.x, acc[6]);
                acc[7] = fmaf(exa, f3.y, acc[7]);
            }
            if (vb) {
                float2 f0 = __half22float2(*(__half2*)&rb.x);
                float2 f1 = __half22float2(*(__half2*)&rb.y);
                float2 f2 = __half22float2(*(__half2*)&rb.z);
                float2 f3 = __half22float2(*(__half2*)&rb.w);
                acc[0] = fmaf(exb, f0.x, acc[0]);
                acc[1] = fmaf(exb, f0.y, acc[1]);
                acc[2] = fmaf(exb, f1.x, acc[2]);
                acc[3] = fmaf(exb, f1.y, acc[3]);
                acc[4] = fmaf(exb, f2.x, acc[4]);
                acc[5] = fmaf(exb, f2.y, acc[5]);
                acc[6] = fmaf(exb, f3.x, acc[6]);
                acc[7] = fmaf(exb, f3.y, acc[7]);
            }
        }
#pragma unroll
        for (int off = 8; off < 64; off <<= 1) {
#pragma unroll
            for (int j = 0; j < 8; ++j) acc[j] += __shfl_xor(acc[j], off);
        }
        if (esub == 0) {
            float inv = 1.f / (denom + EPS_F);
            const float4 b0 = *(const float4*)&b[fg * 8];
            const float4 b1 = *(const float4*)&b[fg * 8 + 4];
            float4 o0, o1;
            o0.x = acc[0] * inv + b0.x;
            o0.y = acc[1] * inv + b0.y;
            o0.z = acc[2] * inv + b0.z;
            o0.w = acc[3] * inv + b0.w;
            o1.x = acc[4] * inv + b1.x;
            o1.y = acc[5] * inv + b1.y;
            o1.z = acc[6] * inv + b1.z;
            o1.w = acc[7] * inv + b1.w;
            *(float4*)&out[(size_t)wid * HDIM + fg * 8] = o0;
            *(float4*)&out[(size_t)wid * HDIM + fg * 8 + 4] = o1;
        }
        return;
    }

    // ---- slow path (deg > 64): previous verified code ----
    float m = 0.f;
    for (int k = start + lane; k < end; k += 64)
        m = fmaxf(m, als[csr_src[k]] + aldd);
#pragma unroll
    for (int off = 32; off; off >>= 1) m = fmaxf(m, __shfl_xor(m, off));

    const int esub = lane >> 4, fg = lane & 15;
    float4 acc = make_float4(0.f, 0.f, 0.f, 0.f);
    float denom = 0.f;
    for (int k0 = start; k0 < end; k0 += 8) {
        int ka = k0 + esub, kb = k0 + 4 + esub;
        float exa = 0.f, exb = 0.f;
        uint2 ra = make_uint2(0u, 0u), rb = make_uint2(0u, 0u);
        if (ka < end) {
            int s = csr_src[ka];
            float l = als[s] + aldd;
            l = l > 0.f ? l : 0.f;
            exa = __expf(l - m);
            ra = *(const uint2*)&hs[(size_t)s * HDIM + fg * 4];
        }
        if (kb < end) {
            int s = csr_src[kb];
            float l = als[s] + aldd;
            l = l > 0.f ? l : 0.f;
            exb = __expf(l - m);
            rb = *(const uint2*)&hs[(size_t)s * HDIM + fg * 4];
        }
        denom += exa + exb;
        float2 fa0 = __half22float2(*(__half2*)&ra.x);
        float2 fa1 = __half22float2(*(__half2*)&ra.y);
        float2 fb0 = __half22float2(*(__half2*)&rb.x);
        float2 fb1 = __half22float2(*(__half2*)&rb.y);
        acc.x = fmaf(exa, fa0.x, acc.x);
        acc.y = fmaf(exa, fa0.y, acc.y);
        acc.z = fmaf(exa, fa1.x, acc.z);
        acc.w = fmaf(exa, fa1.y, acc.w);
        acc.x = fmaf(exb, fb0.x, acc.x);
        acc.y = fmaf(exb, fb0.y, acc.y);
        acc.z = fmaf(exb, fb1.x, acc.z);
        acc.w = fmaf(exb, fb1.y, acc.w);
    }
#pragma unroll
    for (int off = 16; off < 64; off <<= 1) {
        acc.x += __shfl_xor(acc.x, off);
        acc.y += __shfl_xor(acc.y, off);
        acc.z += __shfl_xor(acc.z, off);
        acc.w += __shfl_xor(acc.w, off);
        denom += __shfl_xor(denom, off);
    }
    if (esub == 0) {
        float inv = 1.f / (denom + EPS_F);
        const float4 b4 = *(const float4*)&b[fg * 4];
        float4 o;
        o.x = acc.x * inv + b4.x;
        o.y = acc.y * inv + b4.y;
        o.z = acc.z * inv + b4.z;
        o.w = acc.w * inv + b4.w;
        *(float4*)&out[(size_t)wid * HDIM + fg * 4] = o;
    }
}

// ---------------------------------------------------------------------------
extern "C" void kernel_launch(void* const* d_in, const int* in_sizes, int n_in,
                              void* d_out, int out_size, void* d_ws, size_t ws_size,
                              hipStream_t stream) {
    const float* x = (const float*)d_in[0];
    const int* ei = (const int*)d_in[1];
    const int E = in_sizes[1] / 2;
    const int din1 = in_sizes[2] / HDIM;  // 128
    const int N = in_sizes[0] / din1;     // 100000
    const int* src = ei;
    const int* dst = ei + E;

    const float* P[15];
    for (int i = 0; i < 15; ++i) P[i] = (const float*)d_in[2 + i];

    // workspace carve-up (16B-aligned chunks first)
    float* w = (float*)d_ws;
    __half* hs = (__half*)w;  w += (size_t)N * HDIM / 2;   // N*64 halves
    float* xb = w;            w += (size_t)N * HDIM;
    float* als = w;           w += N;
    float* ald = w;           w += N;
    float* vd = w;            w += 256;
    int* ip = (int*)w;
    int2* ebuf = (int2*)ip;   ip += 2 * (size_t)E;          // (src,dst) pairs
    int* csr_src = ip;        ip += E;
    int* rowptr = ip;         ip += N + 1;
    int* gbucket = ip;        ip += 256;
    int* bucket_base = ip;    ip += 257;
    int* bucket_cur = ip;     ip += 256;

    const int BT = 256;
    const int gridN32 = (N + 31) / 32;
    const int nbuk = (N + 511) >> BSH;               // 196
    const int gridCH = (E + CH - 1) / CH;            // 196
    const int gridSparse = (N * 64 + BT - 1) / BT;   // 1 wave per node

    // ---- CSR build (once; same edge_index for all 3 layers) ----
    zero_kernel<<<1, 256, 0, stream>>>(gbucket, 256);
    bucket_hist_kernel<<<gridCH, BT, 0, stream>>>(dst, gbucket, E);
    bucket_scan_kernel<<<1, BT, 0, stream>>>(gbucket, bucket_base, bucket_cur, nbuk, E);
    bin_kernel<<<gridCH, BT, 0, stream>>>(src, dst, bucket_cur, ebuf, E);
    bucket_sort_kernel<<<nbuk, BT, 0, stream>>>(ebuf, bucket_base, rowptr, csr_src, N, E);

    // ---- per-layer destination attention vectors, one launch ----
    compute_vd_all_kernel<<<3, 128, 0, stream>>>(P[1], P[3], P[6], P[8], P[11], P[13], vd);

    auto run_layer = [&](const float* xin, int din, const float* Ws, const float* vdl,
                         const float* as_, const float* b, float* xout) {
        if (din == 128)
            gemm_fused_kernel<128><<<gridN32, BT, 0, stream>>>(xin, Ws, as_, vdl, hs, als, ald, N);
        else
            gemm_fused_kernel<64><<<gridN32, BT, 0, stream>>>(xin, Ws, as_, vdl, hs, als, ald, N);
        gat_sparse_kernel<<<gridSparse, BT, 0, stream>>>(rowptr, csr_src, als, ald, hs, b,
                                                         xout, N);
    };

    float* out = (float*)d_out;
    run_layer(x,   din1, P[0],  vd,       P[2],  P[4],  xb);
    run_layer(xb,  HDIM, P[5],  vd + 128, P[7],  P[9],  out);
    run_layer(out, HDIM, P[10], vd + 192, P[12], P[14], out);
}

// Round 10
// 414.373 us; speedup vs baseline: 4.2387x; 1.0520x over previous
//
#include <hip/hip_runtime.h>
#include <hip/hip_fp16.h>

#define HDIM 64
#define EPS_F 1e-16f
#define CH 8192          // edges per block in binning/hist passes
#define BSH 9            // bucket shift: 512 nodes per bucket
#define SRCB 17          // src bits in packed ebuf (N < 131072)

// ---------------------------------------------------------------------------
// vd for all 3 layers in one launch: vd[k] = sum_j Wd[k][j]*a_d[j]
// layout: vd1[0:128), vd2[128:192), vd3[192:256)
// ---------------------------------------------------------------------------
__global__ void compute_vd_all_kernel(const float* __restrict__ Wd1, const float* __restrict__ ad1,
                                      const float* __restrict__ Wd2, const float* __restrict__ ad2,
                                      const float* __restrict__ Wd3, const float* __restrict__ ad3,
                                      float* __restrict__ vd) {
    int l = blockIdx.x;
    int k = threadIdx.x;
    const float* Wd = (l == 0) ? Wd1 : (l == 1) ? Wd2 : Wd3;
    const float* ad = (l == 0) ? ad1 : (l == 1) ? ad2 : ad3;
    int din = (l == 0) ? 128 : 64;
    int off = (l == 0) ? 0 : (l == 1) ? 128 : 192;
    if (k >= din) return;
    float s = 0.f;
#pragma unroll
    for (int j = 0; j < HDIM; ++j) s = fmaf(Wd[k * HDIM + j], ad[j], s);
    vd[off + k] = s;
}

// ---------------------------------------------------------------------------
// Fused: hs = x @ Ws (stored fp16) ;  als = hs . a_s (f32) ;  ald = x . vd
// ---------------------------------------------------------------------------
template <int DIN>
__global__ __launch_bounds__(256) void gemm_fused_kernel(
    const float* __restrict__ xin, const float* __restrict__ Ws,
    const float* __restrict__ as_, const float* __restrict__ vd,
    __half* __restrict__ hs, float* __restrict__ als, float* __restrict__ ald,
    int N) {
    __shared__ float wsh[DIN * HDIM];
    __shared__ float xs[32 * (DIN + 4)];
    __shared__ float ash[HDIM];
    __shared__ float vdsh[DIN];

    const int tid = threadIdx.x;
    const int n0 = blockIdx.x * 32;

    for (int i = tid * 4; i < DIN * HDIM; i += 256 * 4)
        *(float4*)&wsh[i] = *(const float4*)&Ws[i];
    if (tid < HDIM) ash[tid] = as_[tid];
    if (tid < DIN) vdsh[tid] = vd[tid];
    for (int i = tid; i < 32 * DIN / 4; i += 256) {
        int idx = i * 4;
        int n = idx / DIN, k = idx - n * DIN;
        float4 v = make_float4(0.f, 0.f, 0.f, 0.f);
        if (n0 + n < N) v = *(const float4*)&xin[(size_t)(n0 + n) * DIN + k];
        *(float4*)&xs[n * (DIN + 4) + k] = v;
    }
    __syncthreads();

    const int nl = tid >> 3, jg = tid & 7, j0 = jg * 8;
    const int n = n0 + nl;
    float acc[8] = {0.f, 0.f, 0.f, 0.f, 0.f, 0.f, 0.f, 0.f};
    float aldp = 0.f;
    const float* xrow = &xs[nl * (DIN + 4)];
#pragma unroll 4
    for (int k = 0; k < DIN; ++k) {
        float xv = xrow[k];
        aldp = fmaf(xv, vdsh[k], aldp);
        float4 w0 = *(const float4*)&wsh[k * HDIM + j0];
        float4 w1 = *(const float4*)&wsh[k * HDIM + j0 + 4];
        acc[0] = fmaf(xv, w0.x, acc[0]);
        acc[1] = fmaf(xv, w0.y, acc[1]);
        acc[2] = fmaf(xv, w0.z, acc[2]);
        acc[3] = fmaf(xv, w0.w, acc[3]);
        acc[4] = fmaf(xv, w1.x, acc[4]);
        acc[5] = fmaf(xv, w1.y, acc[5]);
        acc[6] = fmaf(xv, w1.z, acc[6]);
        acc[7] = fmaf(xv, w1.w, acc[7]);
    }
    float alsp = 0.f;
#pragma unroll
    for (int jj = 0; jj < 8; ++jj) alsp = fmaf(acc[jj], ash[j0 + jj], alsp);
    alsp += __shfl_down(alsp, 4, 8);
    alsp += __shfl_down(alsp, 2, 8);
    alsp += __shfl_down(alsp, 1, 8);

    if (n < N) {
        union { __half h[8]; float4 f; } u;
#pragma unroll
        for (int jj = 0; jj < 8; ++jj) u.h[jj] = __float2half_rn(acc[jj]);
        *(float4*)&hs[(size_t)n * HDIM + j0] = u.f;   // 16B store of 8 halves
        if (jg == 0) {
            als[n] = alsp;
            ald[n] = aldp;
        }
    }
}

// ---------------------------------------------------------------------------
// CSR build, two-level counting sort by dst. ebuf packed 4B/edge:
// (dst&511)<<SRCB | src   (requires N < 2^SRCB)
// ---------------------------------------------------------------------------
__global__ void zero_kernel(int* __restrict__ p, int n) {
    int i = blockIdx.x * blockDim.x + threadIdx.x;
    if (i < n) p[i] = 0;
}

// coarse histogram over buckets (dst >> BSH), block-aggregated in LDS
__global__ __launch_bounds__(256) void bucket_hist_kernel(const int* __restrict__ dst,
                                                          int* __restrict__ gbucket, int E) {
    __shared__ int bh[256];
    int t = threadIdx.x;
    bh[t] = 0;
    __syncthreads();
    int e0 = blockIdx.x * CH;
#pragma unroll
    for (int i = 0; i < CH / 256; ++i) {
        int e = e0 + i * 256 + t;
        if (e < E) atomicAdd(&bh[dst[e] >> BSH], 1);
    }
    __syncthreads();
    if (bh[t]) atomicAdd(&gbucket[t], bh[t]);
}

// exclusive scan of bucket counts (nbuk <= 256), one block
__global__ __launch_bounds__(256) void bucket_scan_kernel(const int* __restrict__ gbucket,
                                                          int* __restrict__ bucket_base,
                                                          int* __restrict__ bucket_cur,
                                                          int nbuk, int E) {
    __shared__ int tmp[256];
    int t = threadIdx.x;
    int v = (t < nbuk) ? gbucket[t] : 0;
    tmp[t] = v;
    __syncthreads();
    for (int off = 1; off < 256; off <<= 1) {
        int a = (t >= off) ? tmp[t - off] : 0;
        __syncthreads();
        tmp[t] += a;
        __syncthreads();
    }
    int excl = tmp[t] - v;
    if (t < nbuk) {
        bucket_base[t] = excl;
        bucket_cur[t] = excl;
    }
    if (t == 0) bucket_base[nbuk] = E;
}

// pass A: bin edges into buckets; block-local counts -> one bulk reserve per
// bucket -> writes are contiguous runs per bucket (kills line thrash)
__global__ __launch_bounds__(256) void bin_kernel(const int* __restrict__ src,
                                                  const int* __restrict__ dst,
                                                  int* __restrict__ bucket_cur,
                                                  unsigned int* __restrict__ epack, int E) {
    __shared__ int lcnt[256], lbase[256];
    int t = threadIdx.x;
    int e0 = blockIdx.x * CH;
    lcnt[t] = 0;
    __syncthreads();
#pragma unroll
    for (int i = 0; i < CH / 256; ++i) {
        int e = e0 + i * 256 + t;
        if (e < E) atomicAdd(&lcnt[dst[e] >> BSH], 1);
    }
    __syncthreads();
    int c = lcnt[t];
    if (c) lbase[t] = atomicAdd(&bucket_cur[t], c);
    __syncthreads();
    lcnt[t] = 0;
    __syncthreads();
#pragma unroll
    for (int i = 0; i < CH / 256; ++i) {
        int e = e0 + i * 256 + t;
        if (e < E) {
            int d = dst[e];
            int bk = d >> BSH;
            int pos = lbase[bk] + atomicAdd(&lcnt[bk], 1);
            epack[pos] = ((unsigned int)(d & 511) << SRCB) | (unsigned int)src[e];
        }
    }
}

// pass B: one block per bucket; LDS counting sort over 512-node range.
__global__ __launch_bounds__(256) void bucket_sort_kernel(
    const unsigned int* __restrict__ epack, const int* __restrict__ bucket_base,
    int* __restrict__ rowptr, int* __restrict__ csr_src, int N, int E) {
    __shared__ int cnt[512], cur[512], psum[256];
    int b = blockIdx.x, t = threadIdx.x;
    int n0 = b << BSH;
    int nlocal = min(512, N - n0);
    int bstart = bucket_base[b], bend = bucket_base[b + 1];
    cnt[t] = 0;
    cnt[t + 256] = 0;
    __syncthreads();
    for (int k = bstart + t; k < bend; k += 256)
        atomicAdd(&cnt[epack[k] >> SRCB], 1);
    __syncthreads();
    int p = cnt[2 * t] + cnt[2 * t + 1];
    psum[t] = p;
    __syncthreads();
    for (int off = 1; off < 256; off <<= 1) {
        int a = (t >= off) ? psum[t - off] : 0;
        __syncthreads();
        psum[t] += a;
        __syncthreads();
    }
    int excl = psum[t] - p;
    int o0 = excl, o1 = excl + cnt[2 * t];
    cur[2 * t] = o0;
    cur[2 * t + 1] = o1;
    if (2 * t < nlocal) rowptr[n0 + 2 * t] = bstart + o0;
    if (2 * t + 1 < nlocal) rowptr[n0 + 2 * t + 1] = bstart + o1;
    __syncthreads();
    for (int k = bstart + t; k < bend; k += 256) {
        unsigned int e = epack[k];
        int pos = bstart + atomicAdd(&cur[e >> SRCB], 1);
        csr_src[pos] = (int)(e & ((1u << SRCB) - 1u));
    }
    if (b == 0 && t == 0) rowptr[N] = E;
}

// ---------------------------------------------------------------------------
// Fused sparse layer: one wave per dst node.
// FAST PATH (deg <= 64):
//   - NO seg-max: exp(l)/sum(exp(l)) == exp(l-m)/sum(exp(l-m)) exactly;
//     logits ~O(10), exp(l) ~O(1e4), f32 has 1e38 headroom. Removes the
//     max shuffle-reduce from the serial critical path.
//   - lane=edge: s, ex=exp(relu(l)) kept in registers; denom via 6 shfl
//     (hides under phase-B gather latency).
//   - phase B: 16 lanes/edge (uint2 = 4 halves), 8 edges in flight/iter,
//     branchless (invalid edges gather row 0 with weight 0);
//     scalar __half2float+fmaf so compiler can emit v_fma_mix_f32.
//   - final reduce: 2 levels x 4 regs = 8 shfl (vs 24 at 8 lanes/edge).
// SLOW PATH (deg > 64, ~never at Poisson(16)): previous verified code.
// ---------------------------------------------------------------------------
__global__ __launch_bounds__(256) void gat_sparse_kernel(
    const int* __restrict__ rowptr, const int* __restrict__ csr_src,
    const float* __restrict__ als, const float* __restrict__ ald,
    const __half* __restrict__ hs, const float* __restrict__ b,
    float* __restrict__ out, int N) {
    int wid = (blockIdx.x * 256 + threadIdx.x) >> 6;  // node id
    int lane = threadIdx.x & 63;
    if (wid >= N) return;
    int start = rowptr[wid], end = rowptr[wid + 1];
    int deg = end - start;
    float aldd = ald[wid];

    if (deg <= 64) {
        // ---- fast path ----
        bool valid = lane < deg;
        int s = 0;
        float ex = 0.f;
        if (valid) {
            s = csr_src[start + lane];
            float l = als[s] + aldd;
            l = l > 0.f ? l : 0.f;
            ex = __expf(l);           // no max subtraction (see header comment)
        }
        float denom = ex;
#pragma unroll
        for (int off = 32; off; off >>= 1) denom += __shfl_xor(denom, off);

        const int esub = lane >> 4, fg = lane & 15;
        float a0 = 0.f, a1 = 0.f, a2 = 0.f, a3 = 0.f;
        for (int k0 = 0; k0 < deg; k0 += 8) {
            int ia = k0 + esub, ib = k0 + 4 + esub;   // always < 64
            float exa = __shfl(ex, ia), exb = __shfl(ex, ib);
            int sa = __shfl(s, ia), sb = __shfl(s, ib);
            union { uint2 u; __half h[4]; } ra, rb;
            ra.u = *(const uint2*)&hs[(size_t)sa * HDIM + fg * 4];
            rb.u = *(const uint2*)&hs[(size_t)sb * HDIM + fg * 4];
            a0 = fmaf(exa, __half2float(ra.h[0]), a0);
            a1 = fmaf(exa, __half2float(ra.h[1]), a1);
            a2 = fmaf(exa, __half2float(ra.h[2]), a2);
            a3 = fmaf(exa, __half2float(ra.h[3]), a3);
            a0 = fmaf(exb, __half2float(rb.h[0]), a0);
            a1 = fmaf(exb, __half2float(rb.h[1]), a1);
            a2 = fmaf(exb, __half2float(rb.h[2]), a2);
            a3 = fmaf(exb, __half2float(rb.h[3]), a3);
        }
#pragma unroll
        for (int off = 16; off < 64; off <<= 1) {
            a0 += __shfl_xor(a0, off);
            a1 += __shfl_xor(a1, off);
            a2 += __shfl_xor(a2, off);
            a3 += __shfl_xor(a3, off);
        }
        if (esub == 0) {
            float inv = 1.f / (denom + EPS_F);
            const float4 b4 = *(const float4*)&b[fg * 4];
            float4 o;
            o.x = a0 * inv + b4.x;
            o.y = a1 * inv + b4.y;
            o.z = a2 * inv + b4.z;
            o.w = a3 * inv + b4.w;
            *(float4*)&out[(size_t)wid * HDIM + fg * 4] = o;
        }
        return;
    }

    // ---- slow path (deg > 64): previous verified code ----
    float m = 0.f;
    for (int k = start + lane; k < end; k += 64)
        m = fmaxf(m, als[csr_src[k]] + aldd);
#pragma unroll
    for (int off = 32; off; off >>= 1) m = fmaxf(m, __shfl_xor(m, off));

    const int esub = lane >> 4, fg = lane & 15;
    float4 acc = make_float4(0.f, 0.f, 0.f, 0.f);
    float denom = 0.f;
    for (int k0 = start; k0 < end; k0 += 8) {
        int ka = k0 + esub, kb = k0 + 4 + esub;
        float exa = 0.f, exb = 0.f;
        uint2 ra = make_uint2(0u, 0u), rb = make_uint2(0u, 0u);
        if (ka < end) {
            int s = csr_src[ka];
            float l = als[s] + aldd;
            l = l > 0.f ? l : 0.f;
            exa = __expf(l - m);
            ra = *(const uint2*)&hs[(size_t)s * HDIM + fg * 4];
        }
        if (kb < end) {
            int s = csr_src[kb];
            float l = als[s] + aldd;
            l = l > 0.f ? l : 0.f;
            exb = __expf(l - m);
            rb = *(const uint2*)&hs[(size_t)s * HDIM + fg * 4];
        }
        denom += exa + exb;
        float2 fa0 = __half22float2(*(__half2*)&ra.x);
        float2 fa1 = __half22float2(*(__half2*)&ra.y);
        float2 fb0 = __half22float2(*(__half2*)&rb.x);
        float2 fb1 = __half22float2(*(__half2*)&rb.y);
        acc.x = fmaf(exa, fa0.x, acc.x);
        acc.y = fmaf(exa, fa0.y, acc.y);
        acc.z = fmaf(exa, fa1.x, acc.z);
        acc.w = fmaf(exa, fa1.y, acc.w);
        acc.x = fmaf(exb, fb0.x, acc.x);
        acc.y = fmaf(exb, fb0.y, acc.y);
        acc.z = fmaf(exb, fb1.x, acc.z);
        acc.w = fmaf(exb, fb1.y, acc.w);
    }
#pragma unroll
    for (int off = 16; off < 64; off <<= 1) {
        acc.x += __shfl_xor(acc.x, off);
        acc.y += __shfl_xor(acc.y, off);
        acc.z += __shfl_xor(acc.z, off);
        acc.w += __shfl_xor(acc.w, off);
        denom += __shfl_xor(denom, off);
    }
    if (esub == 0) {
        float inv = 1.f / (denom + EPS_F);
        const float4 b4 = *(const float4*)&b[fg * 4];
        float4 o;
        o.x = acc.x * inv + b4.x;
        o.y = acc.y * inv + b4.y;
        o.z = acc.z * inv + b4.z;
        o.w = acc.w * inv + b4.w;
        *(float4*)&out[(size_t)wid * HDIM + fg * 4] = o;
    }
}

// ---------------------------------------------------------------------------
extern "C" void kernel_launch(void* const* d_in, const int* in_sizes, int n_in,
                              void* d_out, int out_size, void* d_ws, size_t ws_size,
                              hipStream_t stream) {
    const float* x = (const float*)d_in[0];
    const int* ei = (const int*)d_in[1];
    const int E = in_sizes[1] / 2;
    const int din1 = in_sizes[2] / HDIM;  // 128
    const int N = in_sizes[0] / din1;     // 100000 (< 2^SRCB)
    const int* src = ei;
    const int* dst = ei + E;

    const float* P[15];
    for (int i = 0; i < 15; ++i) P[i] = (const float*)d_in[2 + i];

    // workspace carve-up (16B-aligned chunks first)
    float* w = (float*)d_ws;
    __half* hs = (__half*)w;  w += (size_t)N * HDIM / 2;   // N*64 halves
    float* xb = w;            w += (size_t)N * HDIM;
    float* als = w;           w += N;
    float* ald = w;           w += N;
    float* vd = w;            w += 256;
    int* ip = (int*)w;
    unsigned int* epack = (unsigned int*)ip; ip += E;       // packed (dstLocal,src)
    int* csr_src = ip;        ip += E;
    int* rowptr = ip;         ip += N + 1;
    int* gbucket = ip;        ip += 256;
    int* bucket_base = ip;    ip += 257;
    int* bucket_cur = ip;     ip += 256;

    const int BT = 256;
    const int gridN32 = (N + 31) / 32;
    const int nbuk = (N + 511) >> BSH;               // 196
    const int gridCH = (E + CH - 1) / CH;            // 196
    const int gridSparse = (N * 64 + BT - 1) / BT;   // 1 wave per node

    // ---- CSR build (once; same edge_index for all 3 layers) ----
    zero_kernel<<<1, 256, 0, stream>>>(gbucket, 256);
    bucket_hist_kernel<<<gridCH, BT, 0, stream>>>(dst, gbucket, E);
    bucket_scan_kernel<<<1, BT, 0, stream>>>(gbucket, bucket_base, bucket_cur, nbuk, E);
    bin_kernel<<<gridCH, BT, 0, stream>>>(src, dst, bucket_cur, epack, E);
    bucket_sort_kernel<<<nbuk, BT, 0, stream>>>(epack, bucket_base, rowptr, csr_src, N, E);

    // ---- per-layer destination attention vectors, one launch ----
    compute_vd_all_kernel<<<3, 128, 0, stream>>>(P[1], P[3], P[6], P[8], P[11], P[13], vd);

    auto run_layer = [&](const float* xin, int din, const float* Ws, const float* vdl,
                         const float* as_, const float* b, float* xout) {
        if (din == 128)
            gemm_fused_kernel<128><<<gridN32, BT, 0, stream>>>(xin, Ws, as_, vdl, hs, als, ald, N);
        else
            gemm_fused_kernel<64><<<gridN32, BT, 0, stream>>>(xin, Ws, as_, vdl, hs, als, ald, N);
        gat_sparse_kernel<<<gridSparse, BT, 0, stream>>>(rowptr, csr_src, als, ald, hs, b,
                                                         xout, N);
    };

    float* out = (float*)d_out;
    run_layer(x,   din1, P[0],  vd,       P[2],  P[4],  xb);
    run_layer(xb,  HDIM, P[5],  vd + 128, P[7],  P[9],  out);
    run_layer(out, HDIM, P[10], vd + 192, P[12], P[14], out);
}

// Round 11
// 380.238 us; speedup vs baseline: 4.6192x; 1.0898x over previous
//
#include <hip/hip_runtime.h>
#include <hip/hip_fp16.h>

#define HDIM 64
#define EPS_F 1e-16f
#define CH 8192          // edges per block in binning/hist passes
#define BSH 9            // bucket shift: 512 nodes per bucket
#define SRCB 17          // src bits in packed ebuf (N < 131072)

using half8  = __attribute__((ext_vector_type(8))) _Float16;
using floatx4 = __attribute__((ext_vector_type(4))) float;

// ---------------------------------------------------------------------------
// Per-layer B-matrix prep: wt = fp16 [80][DIN] where rows 0..63 = Ws^T,
// row 64 = u = Ws@a_s (so als = x.u), row 65 = v = Wd@a_d (ald = x.v),
// rows 66..79 = 0 (pad to 5 MFMA j-tiles).
// ---------------------------------------------------------------------------
__global__ void build_wt_kernel(const float* __restrict__ Ws, const float* __restrict__ as_,
                                const float* __restrict__ Wd, const float* __restrict__ ad,
                                _Float16* __restrict__ wt, int din) {
    int tid = threadIdx.x;
    for (int idx = tid; idx < 64 * din; idx += 256) {
        int c = idx / din, k = idx - c * din;
        wt[c * din + k] = (_Float16)Ws[k * 64 + c];
    }
    for (int k = tid; k < din; k += 256) {
        float u = 0.f, v = 0.f;
#pragma unroll
        for (int j = 0; j < 64; ++j) {
            u = fmaf(Ws[k * 64 + j], as_[j], u);
            v = fmaf(Wd[k * 64 + j], ad[j], v);
        }
        wt[64 * din + k] = (_Float16)u;
        wt[65 * din + k] = (_Float16)v;
    }
    for (int idx = tid; idx < 14 * din; idx += 256) wt[66 * din + idx] = (_Float16)0.f;
}

// ---------------------------------------------------------------------------
// MFMA GEMM: hs[N][64] (fp16) = x @ Ws ; als = x.u ; ald = x.v
// Block: 256 thr = 4 waves; tile 64 nodes x 80 cols; K = DIN (128 or 64).
// LDS tiles XOR-swizzled on the 16B (8-half) block index to avoid the
// 16-way row-stride bank conflict on ds_read_b128 (T2).
// Fragment maps (v_mfma_f32_16x16x32_f16):
//   A: lane l -> row l&15, k = (l>>4)*8 + j  (8 contiguous halves = b128)
//   B: lane l -> col l&15, k = (l>>4)*8 + j  (read from transposed wt)
//   C/D: col = l&15, row = (l>>4)*4 + reg    [m89-verified]
// ---------------------------------------------------------------------------
template <int DIN, bool F32IN>
__global__ __launch_bounds__(256) void gemm_mfma_kernel(
    const void* __restrict__ xin, const _Float16* __restrict__ wt,
    _Float16* __restrict__ hs, float* __restrict__ als, float* __restrict__ ald, int N) {
    constexpr int KB = DIN / 8;     // 16B blocks per row
    __shared__ _Float16 xs[64 * DIN];
    __shared__ _Float16 ws[80 * DIN];
    const int tid = threadIdx.x;
    const int n0 = blockIdx.x * 64;

    // stage B (swizzled)
    for (int c = tid; c < 80 * KB; c += 256) {
        int row = c / KB, kb = c - row * KB;
        half8 v = *(const half8*)&wt[row * DIN + kb * 8];
        *(half8*)&ws[row * DIN + ((kb ^ (row & 7)) * 8)] = v;
    }
    // stage A tile (convert f32->f16 for layer 1), swizzled
    if (F32IN) {
        const float* xf = (const float*)xin;
        for (int c = tid; c < 64 * KB; c += 256) {
            int row = c / KB, kb = c - row * KB;
            int n = n0 + row;
            half8 v;
#pragma unroll
            for (int j = 0; j < 8; ++j) v[j] = (_Float16)0.f;
            if (n < N) {
                const float* p = &xf[(size_t)n * DIN + kb * 8];
                float4 f0 = *(const float4*)p;
                float4 f1 = *(const float4*)(p + 4);
                v[0] = (_Float16)f0.x; v[1] = (_Float16)f0.y;
                v[2] = (_Float16)f0.z; v[3] = (_Float16)f0.w;
                v[4] = (_Float16)f1.x; v[5] = (_Float16)f1.y;
                v[6] = (_Float16)f1.z; v[7] = (_Float16)f1.w;
            }
            *(half8*)&xs[row * DIN + ((kb ^ (row & 7)) * 8)] = v;
        }
    } else {
        const _Float16* xh = (const _Float16*)xin;
        for (int c = tid; c < 64 * KB; c += 256) {
            int row = c / KB, kb = c - row * KB;
            int n = n0 + row;
            half8 v;
#pragma unroll
            for (int j = 0; j < 8; ++j) v[j] = (_Float16)0.f;
            if (n < N) v = *(const half8*)&xh[(size_t)n * DIN + kb * 8];
            *(half8*)&xs[row * DIN + ((kb ^ (row & 7)) * 8)] = v;
        }
    }
    __syncthreads();

    const int lane = tid & 63, wave = tid >> 6;
    const int r16 = lane & 15, kg = lane >> 4;
    const int arow = wave * 16 + r16;

    floatx4 acc[5];
#pragma unroll
    for (int t = 0; t < 5; ++t)
#pragma unroll
        for (int r = 0; r < 4; ++r) acc[t][r] = 0.f;

#pragma unroll
    for (int ks = 0; ks < DIN / 32; ++ks) {
        int kbb = ks * 4 + kg;
        half8 a = *(const half8*)&xs[arow * DIN + ((kbb ^ (arow & 7)) * 8)];
        // (t*16 + r16) & 7 == r16 & 7 for all tiles -> one swizzle term
        int bswz = (kbb ^ (r16 & 7)) * 8;
        half8 b0 = *(const half8*)&ws[(r16)*DIN + bswz];
        half8 b1 = *(const half8*)&ws[(16 + r16) * DIN + bswz];
        half8 b2 = *(const half8*)&ws[(32 + r16) * DIN + bswz];
        half8 b3 = *(const half8*)&ws[(48 + r16) * DIN + bswz];
        half8 b4 = *(const half8*)&ws[(64 + r16) * DIN + bswz];
        acc[0] = __builtin_amdgcn_mfma_f32_16x16x32_f16(a, b0, acc[0], 0, 0, 0);
        acc[1] = __builtin_amdgcn_mfma_f32_16x16x32_f16(a, b1, acc[1], 0, 0, 0);
        acc[2] = __builtin_amdgcn_mfma_f32_16x16x32_f16(a, b2, acc[2], 0, 0, 0);
        acc[3] = __builtin_amdgcn_mfma_f32_16x16x32_f16(a, b3, acc[3], 0, 0, 0);
        acc[4] = __builtin_amdgcn_mfma_f32_16x16x32_f16(a, b4, acc[4], 0, 0, 0);
    }

    // epilogue: transpose hs tiles through LDS (reuse ws), coalesced b128 out
    __syncthreads();
    constexpr int OS = 72;           // halves; 144B row stride (16B-aligned)
    _Float16* os = ws;               // 64*72 halves <= 80*DIN halves
#pragma unroll
    for (int t = 0; t < 4; ++t)
#pragma unroll
        for (int r = 0; r < 4; ++r) {
            int row = wave * 16 + kg * 4 + r;
            os[row * OS + t * 16 + r16] = (_Float16)acc[t][r];
        }
    __syncthreads();
    for (int c = tid; c < 64 * 8; c += 256) {
        int row = c >> 3, kb = c & 7;
        int n = n0 + row;
        if (n < N)
            *(half8*)&hs[(size_t)n * HDIM + kb * 8] = *(const half8*)&os[row * OS + kb * 8];
    }
    if (r16 < 2) {
        float* dst = (r16 == 0) ? als : ald;
#pragma unroll
        for (int r = 0; r < 4; ++r) {
            int n = n0 + wave * 16 + kg * 4 + r;
            if (n < N) dst[n] = acc[4][r];
        }
    }
}

// ---------------------------------------------------------------------------
// CSR build, two-level counting sort by dst. ebuf packed 4B/edge.
// ---------------------------------------------------------------------------
__global__ void zero_kernel(int* __restrict__ p, int n) {
    int i = blockIdx.x * blockDim.x + threadIdx.x;
    if (i < n) p[i] = 0;
}

__global__ __launch_bounds__(256) void bucket_hist_kernel(const int* __restrict__ dst,
                                                          int* __restrict__ gbucket, int E) {
    __shared__ int bh[256];
    int t = threadIdx.x;
    bh[t] = 0;
    __syncthreads();
    int e0 = blockIdx.x * CH;
#pragma unroll
    for (int i = 0; i < CH / 256; ++i) {
        int e = e0 + i * 256 + t;
        if (e < E) atomicAdd(&bh[dst[e] >> BSH], 1);
    }
    __syncthreads();
    if (bh[t]) atomicAdd(&gbucket[t], bh[t]);
}

__global__ __launch_bounds__(256) void bucket_scan_kernel(const int* __restrict__ gbucket,
                                                          int* __restrict__ bucket_base,
                                                          int* __restrict__ bucket_cur,
                                                          int nbuk, int E) {
    __shared__ int tmp[256];
    int t = threadIdx.x;
    int v = (t < nbuk) ? gbucket[t] : 0;
    tmp[t] = v;
    __syncthreads();
    for (int off = 1; off < 256; off <<= 1) {
        int a = (t >= off) ? tmp[t - off] : 0;
        __syncthreads();
        tmp[t] += a;
        __syncthreads();
    }
    int excl = tmp[t] - v;
    if (t < nbuk) {
        bucket_base[t] = excl;
        bucket_cur[t] = excl;
    }
    if (t == 0) bucket_base[nbuk] = E;
}

__global__ __launch_bounds__(256) void bin_kernel(const int* __restrict__ src,
                                                  const int* __restrict__ dst,
                                                  int* __restrict__ bucket_cur,
                                                  unsigned int* __restrict__ epack, int E) {
    __shared__ int lcnt[256], lbase[256];
    int t = threadIdx.x;
    int e0 = blockIdx.x * CH;
    lcnt[t] = 0;
    __syncthreads();
#pragma unroll
    for (int i = 0; i < CH / 256; ++i) {
        int e = e0 + i * 256 + t;
        if (e < E) atomicAdd(&lcnt[dst[e] >> BSH], 1);
    }
    __syncthreads();
    int c = lcnt[t];
    if (c) lbase[t] = atomicAdd(&bucket_cur[t], c);
    __syncthreads();
    lcnt[t] = 0;
    __syncthreads();
#pragma unroll
    for (int i = 0; i < CH / 256; ++i) {
        int e = e0 + i * 256 + t;
        if (e < E) {
            int d = dst[e];
            int bk = d >> BSH;
            int pos = lbase[bk] + atomicAdd(&lcnt[bk], 1);
            epack[pos] = ((unsigned int)(d & 511) << SRCB) | (unsigned int)src[e];
        }
    }
}

__global__ __launch_bounds__(256) void bucket_sort_kernel(
    const unsigned int* __restrict__ epack, const int* __restrict__ bucket_base,
    int* __restrict__ rowptr, int* __restrict__ csr_src, int N, int E) {
    __shared__ int cnt[512], cur[512], psum[256];
    int b = blockIdx.x, t = threadIdx.x;
    int n0 = b << BSH;
    int nlocal = min(512, N - n0);
    int bstart = bucket_base[b], bend = bucket_base[b + 1];
    cnt[t] = 0;
    cnt[t + 256] = 0;
    __syncthreads();
    for (int k = bstart + t; k < bend; k += 256)
        atomicAdd(&cnt[epack[k] >> SRCB], 1);
    __syncthreads();
    int p = cnt[2 * t] + cnt[2 * t + 1];
    psum[t] = p;
    __syncthreads();
    for (int off = 1; off < 256; off <<= 1) {
        int a = (t >= off) ? psum[t - off] : 0;
        __syncthreads();
        psum[t] += a;
        __syncthreads();
    }
    int excl = psum[t] - p;
    int o0 = excl, o1 = excl + cnt[2 * t];
    cur[2 * t] = o0;
    cur[2 * t + 1] = o1;
    if (2 * t < nlocal) rowptr[n0 + 2 * t] = bstart + o0;
    if (2 * t + 1 < nlocal) rowptr[n0 + 2 * t + 1] = bstart + o1;
    __syncthreads();
    for (int k = bstart + t; k < bend; k += 256) {
        unsigned int e = epack[k];
        int pos = bstart + atomicAdd(&cur[e >> SRCB], 1);
        csr_src[pos] = (int)(e & ((1u << SRCB) - 1u));
    }
    if (b == 0 && t == 0) rowptr[N] = E;
}

// ---------------------------------------------------------------------------
// Fused sparse layer (one wave per dst node). F32OUT=true -> write f32 d_out
// (layer 3); else write fp16 next-layer input (halved write traffic).
// ---------------------------------------------------------------------------
template <bool F32OUT>
__global__ __launch_bounds__(256) void gat_sparse_kernel(
    const int* __restrict__ rowptr, const int* __restrict__ csr_src,
    const float* __restrict__ als, const float* __restrict__ ald,
    const __half* __restrict__ hs, const float* __restrict__ b,
    float* __restrict__ out, _Float16* __restrict__ outh, int N) {
    int wid = (blockIdx.x * 256 + threadIdx.x) >> 6;
    int lane = threadIdx.x & 63;
    if (wid >= N) return;
    int start = rowptr[wid], end = rowptr[wid + 1];
    int deg = end - start;
    float aldd = ald[wid];

    if (deg <= 64) {
        bool valid = lane < deg;
        int s = 0;
        float ex = 0.f;
        if (valid) {
            s = csr_src[start + lane];
            float l = als[s] + aldd;
            l = l > 0.f ? l : 0.f;
            ex = __expf(l);   // no max-sub: exactly cancels in the softmax ratio
        }
        float denom = ex;
#pragma unroll
        for (int off = 32; off; off >>= 1) denom += __shfl_xor(denom, off);

        const int esub = lane >> 4, fg = lane & 15;
        float a0 = 0.f, a1 = 0.f, a2 = 0.f, a3 = 0.f;
        for (int k0 = 0; k0 < deg; k0 += 8) {
            int ia = k0 + esub, ib = k0 + 4 + esub;
            float exa = __shfl(ex, ia), exb = __shfl(ex, ib);
            int sa = __shfl(s, ia), sb = __shfl(s, ib);
            union { uint2 u; __half h[4]; } ra, rb;
            ra.u = *(const uint2*)&hs[(size_t)sa * HDIM + fg * 4];
            rb.u = *(const uint2*)&hs[(size_t)sb * HDIM + fg * 4];
            a0 = fmaf(exa, __half2float(ra.h[0]), a0);
            a1 = fmaf(exa, __half2float(ra.h[1]), a1);
            a2 = fmaf(exa, __half2float(ra.h[2]), a2);
            a3 = fmaf(exa, __half2float(ra.h[3]), a3);
            a0 = fmaf(exb, __half2float(rb.h[0]), a0);
            a1 = fmaf(exb, __half2float(rb.h[1]), a1);
            a2 = fmaf(exb, __half2float(rb.h[2]), a2);
            a3 = fmaf(exb, __half2float(rb.h[3]), a3);
        }
#pragma unroll
        for (int off = 16; off < 64; off <<= 1) {
            a0 += __shfl_xor(a0, off);
            a1 += __shfl_xor(a1, off);
            a2 += __shfl_xor(a2, off);
            a3 += __shfl_xor(a3, off);
        }
        if (esub == 0) {
            float inv = 1.f / (denom + EPS_F);
            const float4 b4 = *(const float4*)&b[fg * 4];
            float o0 = a0 * inv + b4.x, o1 = a1 * inv + b4.y;
            float o2 = a2 * inv + b4.z, o3 = a3 * inv + b4.w;
            if (F32OUT) {
                *(float4*)&out[(size_t)wid * HDIM + fg * 4] = make_float4(o0, o1, o2, o3);
            } else {
                union { _Float16 h[4]; uint2 u; } ov;
                ov.h[0] = (_Float16)o0; ov.h[1] = (_Float16)o1;
                ov.h[2] = (_Float16)o2; ov.h[3] = (_Float16)o3;
                *(uint2*)&outh[(size_t)wid * HDIM + fg * 4] = ov.u;
            }
        }
        return;
    }

    // slow path (deg > 64)
    float m = 0.f;
    for (int k = start + lane; k < end; k += 64)
        m = fmaxf(m, als[csr_src[k]] + aldd);
#pragma unroll
    for (int off = 32; off; off >>= 1) m = fmaxf(m, __shfl_xor(m, off));

    const int esub = lane >> 4, fg = lane & 15;
    float4 acc = make_float4(0.f, 0.f, 0.f, 0.f);
    float denom = 0.f;
    for (int k0 = start; k0 < end; k0 += 8) {
        int ka = k0 + esub, kb = k0 + 4 + esub;
        float exa = 0.f, exb = 0.f;
        uint2 ra = make_uint2(0u, 0u), rb = make_uint2(0u, 0u);
        if (ka < end) {
            int s = csr_src[ka];
            float l = als[s] + aldd;
            l = l > 0.f ? l : 0.f;
            exa = __expf(l - m);
            ra = *(const uint2*)&hs[(size_t)s * HDIM + fg * 4];
        }
        if (kb < end) {
            int s = csr_src[kb];
            float l = als[s] + aldd;
            l = l > 0.f ? l : 0.f;
            exb = __expf(l - m);
            rb = *(const uint2*)&hs[(size_t)s * HDIM + fg * 4];
        }
        denom += exa + exb;
        float2 fa0 = __half22float2(*(__half2*)&ra.x);
        float2 fa1 = __half22float2(*(__half2*)&ra.y);
        float2 fb0 = __half22float2(*(__half2*)&rb.x);
        float2 fb1 = __half22float2(*(__half2*)&rb.y);
        acc.x = fmaf(exa, fa0.x, acc.x);
        acc.y = fmaf(exa, fa0.y, acc.y);
        acc.z = fmaf(exa, fa1.x, acc.z);
        acc.w = fmaf(exa, fa1.y, acc.w);
        acc.x = fmaf(exb, fb0.x, acc.x);
        acc.y = fmaf(exb, fb0.y, acc.y);
        acc.z = fmaf(exb, fb1.x, acc.z);
        acc.w = fmaf(exb, fb1.y, acc.w);
    }
#pragma unroll
    for (int off = 16; off < 64; off <<= 1) {
        acc.x += __shfl_xor(acc.x, off);
        acc.y += __shfl_xor(acc.y, off);
        acc.z += __shfl_xor(acc.z, off);
        acc.w += __shfl_xor(acc.w, off);
        denom += __shfl_xor(denom, off);
    }
    if (esub == 0) {
        float inv = 1.f / (denom + EPS_F);
        const float4 b4 = *(const float4*)&b[fg * 4];
        float o0 = acc.x * inv + b4.x, o1 = acc.y * inv + b4.y;
        float o2 = acc.z * inv + b4.z, o3 = acc.w * inv + b4.w;
        if (F32OUT) {
            *(float4*)&out[(size_t)wid * HDIM + fg * 4] = make_float4(o0, o1, o2, o3);
        } else {
            union { _Float16 h[4]; uint2 u; } ov;
            ov.h[0] = (_Float16)o0; ov.h[1] = (_Float16)o1;
            ov.h[2] = (_Float16)o2; ov.h[3] = (_Float16)o3;
            *(uint2*)&outh[(size_t)wid * HDIM + fg * 4] = ov.u;
        }
    }
}

// ---------------------------------------------------------------------------
extern "C" void kernel_launch(void* const* d_in, const int* in_sizes, int n_in,
                              void* d_out, int out_size, void* d_ws, size_t ws_size,
                              hipStream_t stream) {
    const float* x = (const float*)d_in[0];
    const int* ei = (const int*)d_in[1];
    const int E = in_sizes[1] / 2;
    const int din1 = in_sizes[2] / HDIM;  // 128
    const int N = in_sizes[0] / din1;     // 100000 (< 2^SRCB)
    const int* src = ei;
    const int* dst = ei + E;

    const float* P[15];
    for (int i = 0; i < 15; ++i) P[i] = (const float*)d_in[2 + i];

    // workspace carve-up (16B alignment preserved)
    _Float16* hp = (_Float16*)d_ws;
    _Float16* hs = hp;   hp += (size_t)N * HDIM;
    _Float16* xh = hp;   hp += (size_t)N * HDIM;
    _Float16* wt1 = hp;  hp += 80 * 128;
    _Float16* wt2 = hp;  hp += 80 * 64;
    _Float16* wt3 = hp;  hp += 80 * 64;
    float* fp = (float*)hp;
    float* als = fp;     fp += N;
    float* ald = fp;     fp += N;
    int* ip = (int*)fp;
    unsigned int* epack = (unsigned int*)ip; ip += E;
    int* csr_src = ip;   ip += E;
    int* rowptr = ip;    ip += N + 1;
    int* gbucket = ip;   ip += 256;
    int* bucket_base = ip; ip += 257;
    int* bucket_cur = ip;  ip += 256;

    const int BT = 256;
    const int gridG = (N + 63) / 64;                 // MFMA GEMM blocks
    const int nbuk = (N + 511) >> BSH;               // 196
    const int gridCH = (E + CH - 1) / CH;            // 196
    const int gridSparse = (N * 64 + BT - 1) / BT;   // 1 wave per node

    // ---- CSR build (once; shared by all 3 layers) ----
    zero_kernel<<<1, 256, 0, stream>>>(gbucket, 256);
    bucket_hist_kernel<<<gridCH, BT, 0, stream>>>(dst, gbucket, E);
    bucket_scan_kernel<<<1, BT, 0, stream>>>(gbucket, bucket_base, bucket_cur, nbuk, E);
    bin_kernel<<<gridCH, BT, 0, stream>>>(src, dst, bucket_cur, epack, E);
    bucket_sort_kernel<<<nbuk, BT, 0, stream>>>(epack, bucket_base, rowptr, csr_src, N, E);

    // ---- per-layer transposed fp16 B matrices (Ws^T | u | v | 0-pad) ----
    build_wt_kernel<<<1, 256, 0, stream>>>(P[0], P[2], P[1], P[3], wt1, 128);
    build_wt_kernel<<<1, 256, 0, stream>>>(P[5], P[7], P[6], P[8], wt2, 64);
    build_wt_kernel<<<1, 256, 0, stream>>>(P[10], P[12], P[11], P[13], wt3, 64);

    float* out = (float*)d_out;

    // layer 1: x (f32) -> hs/als/ald -> xh (fp16)
    gemm_mfma_kernel<128, true><<<gridG, BT, 0, stream>>>(x, wt1, hs, als, ald, N);
    gat_sparse_kernel<false><<<gridSparse, BT, 0, stream>>>(rowptr, csr_src, als, ald,
                                                            (const __half*)hs, P[4],
                                                            nullptr, xh, N);
    // layer 2: xh (fp16) -> hs -> xh
    gemm_mfma_kernel<64, false><<<gridG, BT, 0, stream>>>(xh, wt2, hs, als, ald, N);
    gat_sparse_kernel<false><<<gridSparse, BT, 0, stream>>>(rowptr, csr_src, als, ald,
                                                            (const __half*)hs, P[9],
                                                            nullptr, xh, N);
    // layer 3: xh -> hs -> d_out (f32)
    gemm_mfma_kernel<64, false><<<gridG, BT, 0, stream>>>(xh, wt3, hs, als, ald, N);
    gat_sparse_kernel<true><<<gridSparse, BT, 0, stream>>>(rowptr, csr_src, als, ald,
                                                           (const __half*)hs, P[14],
                                                           out, nullptr, N);
}